// Round 9
// baseline (160.257 us; speedup 1.0000x reference)
//
#include <hip/hip_runtime.h>
#include <math.h>

#define BB 2
#define SS 2048
#define EE 1024
#define HH 16
#define DD 64
constexpr int NROWS = BB * SS * HH;   // 65536 rows of D=64
// q pre-scale: (1/sqrt(E)) * log2(e) so attention can use exp2 directly
constexpr float SCALE_Q = 1.4426950408889634f / 32.0f;

typedef __attribute__((ext_vector_type(8))) short bf16x8;
typedef __attribute__((ext_vector_type(4))) float f32x4;
typedef __attribute__((ext_vector_type(16))) float f32x16;
typedef __attribute__((ext_vector_type(4))) unsigned u32x4;

__device__ inline ushort f2bf(float f) {
  unsigned u = __builtin_bit_cast(unsigned, f);
  u += 0x7fffu + ((u >> 16) & 1u);   // RNE
  return (ushort)(u >> 16);
}

// packed f32x2 -> bf16x2 (RNE), one VALU inst
__device__ inline unsigned cvt_pk(float lo, float hi) {
  unsigned r;
  asm("v_cvt_pk_bf16_f32 %0, %1, %2" : "=v"(r) : "v"(lo), "v"(hi));
  return r;
}

// ---------------------------------------------------------------------------
// Kernel 0: Wq/Wk/Wv fp32 -> bf16 (12288 elems), once.
// ---------------------------------------------------------------------------
__global__ __launch_bounds__(256) void wqkv_cvt(
    const float* __restrict__ Wq, const float* __restrict__ Wk,
    const float* __restrict__ Wv, ushort* __restrict__ o) {
  int i = blockIdx.x * 256 + threadIdx.x;  // grid 48 * 256 = 12288
  int t = i >> 12, j = i & 4095;
  const float* W = (t == 0) ? Wq : ((t == 1) ? Wk : Wv);
  o[i] = f2bf(W[j]);
}

// ---------------------------------------------------------------------------
// Kernel 1: QKV projection, h-major blocks (fixed b,h; 128 s-rows).
// q,k written [B,S,H,D]; V written TRANSPOSED [B,H,D,S] directly.
// ---------------------------------------------------------------------------
__global__ __launch_bounds__(256) void qkv_mfma(
    const float* __restrict__ x, const ushort* __restrict__ wqkv,
    ushort* __restrict__ qo, ushort* __restrict__ ko, ushort* __restrict__ vto) {
  __shared__ __align__(16) ushort Xs[128 * 72];
  __shared__ __align__(16) ushort Ws[3][64 * 72];
  const int tid = threadIdx.x, w = tid >> 6, l = tid & 63;
  const int g = l >> 4, c = l & 15;
  const int s0 = blockIdx.x * 128, h = blockIdx.y, b = blockIdx.z;

  for (int i = tid; i < 1536; i += 256) {
    int t = i >> 9, j = i & 511;
    int r = j >> 3, e0 = (j & 7) * 8;
    *(bf16x8*)&Ws[t][r * 72 + e0] = *(const bf16x8*)&wqkv[t * 4096 + r * 64 + e0];
  }
  for (int i = tid; i < 2048; i += 256) {
    int r = i >> 4, c4 = (i & 15) * 4;
    float4 xv = *(const float4*)&x[(((size_t)b * SS + s0 + r) * HH + h) * DD + c4];
    uint2 pk;
    pk.x = cvt_pk(xv.x, xv.y);
    pk.y = cvt_pk(xv.z, xv.w);
    *(uint2*)&Xs[r * 72 + c4] = pk;
  }
  __syncthreads();

  bf16x8 a_[2][2];
#pragma unroll
  for (int rf = 0; rf < 2; ++rf) {
    a_[rf][0] = *(bf16x8*)&Xs[(w * 32 + rf * 16 + c) * 72 + g * 8];
    a_[rf][1] = *(bf16x8*)&Xs[(w * 32 + rf * 16 + c) * 72 + 32 + g * 8];
  }

  // q and k: row-major [B,S,H,D]
#pragma unroll
  for (int t = 0; t < 2; ++t) {
    ushort* out = (t == 0) ? qo : ko;
    const float sc = (t == 0) ? SCALE_Q : 1.0f;
#pragma unroll
    for (int ct = 0; ct < 4; ++ct) {
      bf16x8 b0 = *(bf16x8*)&Ws[t][(ct * 16 + c) * 72 + g * 8];
      bf16x8 b1 = *(bf16x8*)&Ws[t][(ct * 16 + c) * 72 + 32 + g * 8];
#pragma unroll
      for (int rf = 0; rf < 2; ++rf) {
        f32x4 acc = (f32x4){0.f, 0.f, 0.f, 0.f};
        acc = __builtin_amdgcn_mfma_f32_16x16x32_bf16(a_[rf][0], b0, acc, 0, 0, 0);
        acc = __builtin_amdgcn_mfma_f32_16x16x32_bf16(a_[rf][1], b1, acc, 0, 0, 0);
#pragma unroll
        for (int r = 0; r < 4; ++r) {
          int srow = w * 32 + rf * 16 + g * 4 + r;
          out[(((size_t)b * SS + s0 + srow) * HH + h) * DD + ct * 16 + c] =
              f2bf(acc[r] * sc);
        }
      }
    }
  }
  // v: transposed [B,H,D,S], packed 8B stores
#pragma unroll
  for (int ct = 0; ct < 4; ++ct) {
    bf16x8 b0 = *(bf16x8*)&Ws[2][(ct * 16 + c) * 72 + g * 8];
    bf16x8 b1 = *(bf16x8*)&Ws[2][(ct * 16 + c) * 72 + 32 + g * 8];
#pragma unroll
    for (int rf = 0; rf < 2; ++rf) {
      f32x4 acc = (f32x4){0.f, 0.f, 0.f, 0.f};
      acc = __builtin_amdgcn_mfma_f32_16x16x32_bf16(a_[rf][0], b0, acc, 0, 0, 0);
      acc = __builtin_amdgcn_mfma_f32_16x16x32_bf16(a_[rf][1], b1, acc, 0, 0, 0);
      uint2 pk;
      pk.x = cvt_pk(acc[0], acc[1]);
      pk.y = cvt_pk(acc[2], acc[3]);
      int d = ct * 16 + c;
      int srow = w * 32 + rf * 16 + g * 4;
      *(uint2*)&vto[(((size_t)b * HH + h) * DD + d) * SS + s0 + srow] = pk;
    }
  }
}

// ---------------------------------------------------------------------------
// Kernel 3: W_out fp32 -> bf16
// ---------------------------------------------------------------------------
__global__ __launch_bounds__(256) void wcvt(const float* __restrict__ w,
                                            ushort* __restrict__ o) {
  int i = (blockIdx.x * 256 + threadIdx.x) * 8;
  bf16x8 t;
#pragma unroll
  for (int j = 0; j < 8; ++j) t[j] = (short)f2bf(w[i + j]);
  *(bf16x8*)&o[i] = t;
}

// ---------------------------------------------------------------------------
// Kernel 4: MFMA flash attention, 32x32x16, swapped S^T = K·Q^T.
// ZERO LDS, ZERO BARRIERS: every lane's K A-frag and V^T A-frag is its own
// 16B slice, loaded global->VGPR through L1/L2 (K/V L2-resident per XCD).
// The sigma permutation (swap key-index bits 2<->3) moves into the K global
// address, so S^T C-regs are already in PV B-frag key order -> P packs with
// 16 cvt_pk. K double-buffered in regs (2-unrolled loop, named buffers);
// V loaded per-iteration (issue-to-use gap = QK+softmax hides L2 latency).
// Each wave owns 32 q-rows; 512 blocks x 4 waves, XCD-chunked.
// ---------------------------------------------------------------------------
__global__ __launch_bounds__(256) void attn_mfma(
    const ushort* __restrict__ q, const ushort* __restrict__ k,
    const ushort* __restrict__ vt, ushort* __restrict__ o) {
  const int tid = threadIdx.x, w = tid >> 6, l = tid & 63;
  const int lq = l & 31, h2 = l >> 5;  // q-col / key-row-half
  // XCD swizzle: blockIdx%8 = XCD -> contiguous chunk of 64 works
  const int work = ((blockIdx.x & 7) << 6) | (blockIdx.x >> 3);
  const int qt = work & 15, hb = work >> 4;
  const int h = hb & 15, b = hb >> 4;
  const int q0 = qt * 128 + w * 32;

  const size_t bh_qk = (size_t)b * SS * EE + h * DD;        // + s*EE + d
  const size_t bh_vt = (size_t)b * SS * EE + h * (DD * SS); // + d*SS + s

  // sigma: swap bits 2 and 3 of the key index (bits 0,1,4 kept)
  const int ksig = (lq & 19) | ((lq & 4) << 1) | ((lq & 8) >> 1);
  const ushort* kbase = k + bh_qk + (size_t)ksig * EE + h2 * 8;
  const ushort* vbase = vt + bh_vt + (size_t)lq * SS + h2 * 8;

  // Q B-frags: lane's q-row = q0 + lq
  bf16x8 aq[4];
#pragma unroll
  for (int db = 0; db < 4; ++db)
    aq[db] = *(const bf16x8*)&q[bh_qk + (size_t)(q0 + lq) * EE + db * 16 + h2 * 8];

  f32x16 accO[2];
  float lacc[2] = {0.f, 0.f};
#pragma unroll
  for (int ct = 0; ct < 2; ++ct)
#pragma unroll
    for (int r = 0; r < 16; ++r) accO[ct][r] = 0.f;

  // K register double-buffers (frag idx = kb*4 + db)
  bf16x8 kfA[8], kfB[8];
  {
    const ushort* ka0 = kbase;
    const ushort* ka1 = kbase + (size_t)32 * EE;
#pragma unroll
    for (int db = 0; db < 4; ++db) {
      kfA[db] = *(const bf16x8*)&ka0[db * 16];
      kfA[4 + db] = *(const bf16x8*)&ka1[db * 16];
    }
  }

  auto body = [&](int tt, bf16x8 (&kcur)[8], bf16x8 (&knxt)[8]) {
    // V^T frags for tile tt (frag idx = ct*4 + kb*2 + t16)
    bf16x8 vf[8];
    const ushort* va0 = vbase + tt * 64;
    const ushort* va1 = va0 + (size_t)32 * SS;
#pragma unroll
    for (int kb = 0; kb < 2; ++kb)
#pragma unroll
      for (int t16 = 0; t16 < 2; ++t16) {
        vf[kb * 2 + t16] = *(const bf16x8*)&va0[kb * 32 + t16 * 16];
        vf[4 + kb * 2 + t16] = *(const bf16x8*)&va1[kb * 32 + t16 * 16];
      }

    // S^T = K Q^T
    f32x16 s[2];
    __builtin_amdgcn_s_setprio(1);
#pragma unroll
    for (int kb = 0; kb < 2; ++kb) {
      f32x16 acc;
#pragma unroll
      for (int r = 0; r < 16; ++r) acc[r] = 0.f;
#pragma unroll
      for (int db = 0; db < 4; ++db)
        acc = __builtin_amdgcn_mfma_f32_32x32x16_bf16(kcur[kb * 4 + db], aq[db],
                                                      acc, 0, 0, 0);
      s[kb] = acc;
    }
    __builtin_amdgcn_s_setprio(0);

    // prefetch K for tile tt+1 (wraps to 0 on last iter; harmless)
    {
      const int tn = (tt + 1) & 31;
      const ushort* ka0 = kbase + (size_t)(tn * 64) * EE;
      const ushort* ka1 = ka0 + (size_t)32 * EE;
#pragma unroll
      for (int db = 0; db < 4; ++db) {
        knxt[db] = *(const bf16x8*)&ka0[db * 16];
        knxt[4 + db] = *(const bf16x8*)&ka1[db * 16];
      }
    }

    // p = exp2(s); regs t16*8+j are exactly PV B-frag key order
    u32x4 pwv[2][2];  // [kb][t16]
#pragma unroll
    for (int kb = 0; kb < 2; ++kb)
#pragma unroll
      for (int t16 = 0; t16 < 2; ++t16)
#pragma unroll
        for (int j2 = 0; j2 < 4; ++j2) {
          float pa = __builtin_amdgcn_exp2f(s[kb][t16 * 8 + j2 * 2]);
          float pb = __builtin_amdgcn_exp2f(s[kb][t16 * 8 + j2 * 2 + 1]);
          lacc[kb] += pa + pb;
          pwv[kb][t16][j2] = cvt_pk(pa, pb);
        }

    // O^T += V^T P^T
    __builtin_amdgcn_s_setprio(1);
#pragma unroll
    for (int ct = 0; ct < 2; ++ct)
#pragma unroll
      for (int kb = 0; kb < 2; ++kb)
#pragma unroll
        for (int t16 = 0; t16 < 2; ++t16)
          accO[ct] = __builtin_amdgcn_mfma_f32_32x32x16_bf16(
              vf[ct * 4 + kb * 2 + t16],
              __builtin_bit_cast(bf16x8, pwv[kb][t16]), accO[ct], 0, 0, 0);
    __builtin_amdgcn_s_setprio(0);
  };

  for (int t = 0; t < 32; t += 2) {
    body(t, kfA, kfB);
    body(t + 1, kfB, kfA);
  }

  // normalize: wave halves hold complementary key sums for the same q
  {
    float tsum = lacc[0] + lacc[1];
    tsum += __shfl_xor(tsum, 32, 64);
    float inv = 1.f / tsum;
    size_t row = (size_t)b * SS + q0 + lq;
#pragma unroll
    for (int ct = 0; ct < 2; ++ct)
#pragma unroll
      for (int rq = 0; rq < 4; ++rq) {
        uint2 pk;
        pk.x = cvt_pk(accO[ct][rq * 4 + 0] * inv, accO[ct][rq * 4 + 1] * inv);
        pk.y = cvt_pk(accO[ct][rq * 4 + 2] * inv, accO[ct][rq * 4 + 3] * inv);
        *(uint2*)&o[row * EE + h * DD + ct * 32 + rq * 8 + h2 * 4] = pk;
      }
  }
}

// ---------------------------------------------------------------------------
// Kernel 5: output projection, bf16 MFMA GEMM, 128x64 tile, reg-staged
// double-buffer, 1 barrier per K-step.
// ---------------------------------------------------------------------------
__global__ __launch_bounds__(256) void out_proj_mfma(
    const ushort* __restrict__ a, const ushort* __restrict__ wo,
    const float* __restrict__ bias, float* __restrict__ y) {
  __shared__ __align__(16) ushort As[2][128 * 72];
  __shared__ __align__(16) ushort Ws[2][64 * 72];
  const int tid = threadIdx.x, w = tid >> 6, l = tid & 63;
  const int g = l >> 4, c = l & 15;
  const int m0 = blockIdx.x * 128, n0 = blockIdx.y * 64;
  const int sr = tid >> 3, se = (tid & 7) * 8;

  f32x4 acc[2][4];
#pragma unroll
  for (int mf = 0; mf < 2; ++mf)
#pragma unroll
    for (int ct = 0; ct < 4; ++ct) acc[mf][ct] = (f32x4){0.f, 0.f, 0.f, 0.f};

  {
#pragma unroll
    for (int j = 0; j < 4; ++j) {
      int r = sr + j * 32;
      *(bf16x8*)&As[0][r * 72 + se] = *(const bf16x8*)&a[(size_t)(m0 + r) * EE + se];
    }
#pragma unroll
    for (int j = 0; j < 2; ++j) {
      int r = sr + j * 32;
      *(bf16x8*)&Ws[0][r * 72 + se] = *(const bf16x8*)&wo[(size_t)(n0 + r) * EE + se];
    }
  }
  __syncthreads();

  for (int t = 0; t < 16; ++t) {
    const int cur = t & 1;
    bf16x8 Arg[4], Brg[2];
    if (t < 15) {
      const int k0 = (t + 1) * 64;
#pragma unroll
      for (int j = 0; j < 4; ++j) {
        int r = sr + j * 32;
        Arg[j] = *(const bf16x8*)&a[(size_t)(m0 + r) * EE + k0 + se];
      }
#pragma unroll
      for (int j = 0; j < 2; ++j) {
        int r = sr + j * 32;
        Brg[j] = *(const bf16x8*)&wo[(size_t)(n0 + r) * EE + k0 + se];
      }
    }

    bf16x8 af[2][2];
#pragma unroll
    for (int mf = 0; mf < 2; ++mf) {
      af[mf][0] = *(bf16x8*)&As[cur][(w * 32 + mf * 16 + c) * 72 + g * 8];
      af[mf][1] = *(bf16x8*)&As[cur][(w * 32 + mf * 16 + c) * 72 + 32 + g * 8];
    }
    __builtin_amdgcn_s_setprio(1);
#pragma unroll
    for (int ct = 0; ct < 4; ++ct) {
      bf16x8 b0 = *(bf16x8*)&Ws[cur][(ct * 16 + c) * 72 + g * 8];
      bf16x8 b1 = *(bf16x8*)&Ws[cur][(ct * 16 + c) * 72 + 32 + g * 8];
#pragma unroll
      for (int mf = 0; mf < 2; ++mf) {
        acc[mf][ct] = __builtin_amdgcn_mfma_f32_16x16x32_bf16(af[mf][0], b0, acc[mf][ct], 0, 0, 0);
        acc[mf][ct] = __builtin_amdgcn_mfma_f32_16x16x32_bf16(af[mf][1], b1, acc[mf][ct], 0, 0, 0);
      }
    }
    __builtin_amdgcn_s_setprio(0);

    if (t < 15) {
      const int nxt = cur ^ 1;
#pragma unroll
      for (int j = 0; j < 4; ++j) {
        int r = sr + j * 32;
        *(bf16x8*)&As[nxt][r * 72 + se] = Arg[j];
      }
#pragma unroll
      for (int j = 0; j < 2; ++j) {
        int r = sr + j * 32;
        *(bf16x8*)&Ws[nxt][r * 72 + se] = Brg[j];
      }
    }
    __syncthreads();
  }

#pragma unroll
  for (int ct = 0; ct < 4; ++ct) {
    float bv = bias[n0 + ct * 16 + c];
#pragma unroll
    for (int mf = 0; mf < 2; ++mf)
#pragma unroll
      for (int r = 0; r < 4; ++r)
        y[(size_t)(m0 + w * 32 + mf * 16 + g * 4 + r) * EE + n0 + ct * 16 + c] =
            acc[mf][ct][r] + bv;
  }
}

// ---------------------------------------------------------------------------
extern "C" void kernel_launch(void* const* d_in, const int* in_sizes, int n_in,
                              void* d_out, int out_size, void* d_ws,
                              size_t ws_size, hipStream_t stream) {
  const float* x = (const float*)d_in[0];
  const float* Wq = (const float*)d_in[1];
  const float* Wk = (const float*)d_in[2];
  const float* Wv = (const float*)d_in[3];
  const float* Wo = (const float*)d_in[4];
  const float* bo = (const float*)d_in[5];
  float* out = (float*)d_out;

  const size_t per = (size_t)NROWS * 64;  // 4,194,304 elems
  ushort* qb = (ushort*)d_ws;                       //  8 MB
  ushort* kb = qb + per;                            //  8 MB
  ushort* vtb = kb + per;                           //  8 MB
  ushort* aob = vtb + per;                          //  8 MB
  ushort* wob = aob + per;                          //  2 MB
  ushort* wqkvb = wob + 1024 * 1024;                // 24 KB

  wqkv_cvt<<<48, 256, 0, stream>>>(Wq, Wk, Wv, wqkvb);
  wcvt<<<512, 256, 0, stream>>>(Wo, wob);
  qkv_mfma<<<dim3(16, 16, 2), 256, 0, stream>>>(x, wqkvb, qb, kb, vtb);
  attn_mfma<<<512, 256, 0, stream>>>(qb, kb, vtb, aob);
  out_proj_mfma<<<dim3(32, 16), 256, 0, stream>>>(aob, wob, bo, out);
}

// Round 10
// 87.443 us; speedup vs baseline: 1.8327x; 1.8327x over previous
//
#include <hip/hip_runtime.h>
#include <math.h>

#define BB 2
#define SS 2048
#define EE 1024
#define HH 16
#define DD 64
constexpr int NROWS = BB * SS * HH;   // 65536 rows of D=64
// q pre-scale: (1/sqrt(E)) * log2(e) so attention can use exp2 directly
constexpr float SCALE_Q = 1.4426950408889634f / 32.0f;

typedef __attribute__((ext_vector_type(8))) short bf16x8;
typedef __attribute__((ext_vector_type(4))) float f32x4;
typedef __attribute__((ext_vector_type(16))) float f32x16;
typedef __attribute__((ext_vector_type(4))) unsigned u32x4;

__device__ inline ushort f2bf(float f) {
  unsigned u = __builtin_bit_cast(unsigned, f);
  u += 0x7fffu + ((u >> 16) & 1u);   // RNE
  return (ushort)(u >> 16);
}

// packed f32x2 -> bf16x2 (RNE), one VALU inst
__device__ inline unsigned cvt_pk(float lo, float hi) {
  unsigned r;
  asm("v_cvt_pk_bf16_f32 %0, %1, %2" : "=v"(r) : "v"(lo), "v"(hi));
  return r;
}

// ---------------------------------------------------------------------------
// Kernel 0: all weight converts in ONE launch.
// groups 0..1535: Wq/Wk/Wv (512 groups of 8 each); groups 1536..133607: W_out.
// ---------------------------------------------------------------------------
__global__ __launch_bounds__(256) void wconv(
    const float* __restrict__ Wq, const float* __restrict__ Wk,
    const float* __restrict__ Wv, const float* __restrict__ Wo,
    ushort* __restrict__ wqkvb, ushort* __restrict__ wob) {
  int idx = blockIdx.x * 256 + threadIdx.x;  // grid 518 * 256 = 132608
  const float* sp;
  ushort* dp;
  if (idx < 1536) {
    int t = idx >> 9, j = idx & 511;
    const float* W = (t == 0) ? Wq : ((t == 1) ? Wk : Wv);
    sp = W + j * 8;
    dp = wqkvb + t * 4096 + j * 8;
  } else {
    size_t j = (size_t)(idx - 1536) * 8;
    sp = Wo + j;
    dp = wob + j;
  }
  float4 a = *(const float4*)sp;
  float4 c = *(const float4*)(sp + 4);
  u32x4 r;
  r[0] = cvt_pk(a.x, a.y);
  r[1] = cvt_pk(a.z, a.w);
  r[2] = cvt_pk(c.x, c.y);
  r[3] = cvt_pk(c.z, c.w);
  *(u32x4*)dp = r;
}

// ---------------------------------------------------------------------------
// Kernel 1: QKV projection, h-major blocks (fixed b,h; 128 s-rows).
// q,k written [B,S,H,D]; V written TRANSPOSED [B,H,D,S] directly.
// ---------------------------------------------------------------------------
__global__ __launch_bounds__(256) void qkv_mfma(
    const float* __restrict__ x, const ushort* __restrict__ wqkv,
    ushort* __restrict__ qo, ushort* __restrict__ ko, ushort* __restrict__ vto) {
  __shared__ __align__(16) ushort Xs[128 * 72];
  __shared__ __align__(16) ushort Ws[3][64 * 72];
  const int tid = threadIdx.x, w = tid >> 6, l = tid & 63;
  const int g = l >> 4, c = l & 15;
  const int s0 = blockIdx.x * 128, h = blockIdx.y, b = blockIdx.z;

  for (int i = tid; i < 1536; i += 256) {
    int t = i >> 9, j = i & 511;
    int r = j >> 3, e0 = (j & 7) * 8;
    *(bf16x8*)&Ws[t][r * 72 + e0] = *(const bf16x8*)&wqkv[t * 4096 + r * 64 + e0];
  }
  for (int i = tid; i < 2048; i += 256) {
    int r = i >> 4, c4 = (i & 15) * 4;
    float4 xv = *(const float4*)&x[(((size_t)b * SS + s0 + r) * HH + h) * DD + c4];
    uint2 pk;
    pk.x = cvt_pk(xv.x, xv.y);
    pk.y = cvt_pk(xv.z, xv.w);
    *(uint2*)&Xs[r * 72 + c4] = pk;
  }
  __syncthreads();

  bf16x8 a_[2][2];
#pragma unroll
  for (int rf = 0; rf < 2; ++rf) {
    a_[rf][0] = *(bf16x8*)&Xs[(w * 32 + rf * 16 + c) * 72 + g * 8];
    a_[rf][1] = *(bf16x8*)&Xs[(w * 32 + rf * 16 + c) * 72 + 32 + g * 8];
  }

  // q and k: row-major [B,S,H,D]
#pragma unroll
  for (int t = 0; t < 2; ++t) {
    ushort* out = (t == 0) ? qo : ko;
    const float sc = (t == 0) ? SCALE_Q : 1.0f;
#pragma unroll
    for (int ct = 0; ct < 4; ++ct) {
      bf16x8 b0 = *(bf16x8*)&Ws[t][(ct * 16 + c) * 72 + g * 8];
      bf16x8 b1 = *(bf16x8*)&Ws[t][(ct * 16 + c) * 72 + 32 + g * 8];
#pragma unroll
      for (int rf = 0; rf < 2; ++rf) {
        f32x4 acc = (f32x4){0.f, 0.f, 0.f, 0.f};
        acc = __builtin_amdgcn_mfma_f32_16x16x32_bf16(a_[rf][0], b0, acc, 0, 0, 0);
        acc = __builtin_amdgcn_mfma_f32_16x16x32_bf16(a_[rf][1], b1, acc, 0, 0, 0);
#pragma unroll
        for (int r = 0; r < 4; ++r) {
          int srow = w * 32 + rf * 16 + g * 4 + r;
          out[(((size_t)b * SS + s0 + srow) * HH + h) * DD + ct * 16 + c] =
              f2bf(acc[r] * sc);
        }
      }
    }
  }
  // v: transposed [B,H,D,S], packed 8B stores
#pragma unroll
  for (int ct = 0; ct < 4; ++ct) {
    bf16x8 b0 = *(bf16x8*)&Ws[2][(ct * 16 + c) * 72 + g * 8];
    bf16x8 b1 = *(bf16x8*)&Ws[2][(ct * 16 + c) * 72 + 32 + g * 8];
#pragma unroll
    for (int rf = 0; rf < 2; ++rf) {
      f32x4 acc = (f32x4){0.f, 0.f, 0.f, 0.f};
      acc = __builtin_amdgcn_mfma_f32_16x16x32_bf16(a_[rf][0], b0, acc, 0, 0, 0);
      acc = __builtin_amdgcn_mfma_f32_16x16x32_bf16(a_[rf][1], b1, acc, 0, 0, 0);
      uint2 pk;
      pk.x = cvt_pk(acc[0], acc[1]);
      pk.y = cvt_pk(acc[2], acc[3]);
      int d = ct * 16 + c;
      int srow = w * 32 + rf * 16 + g * 4;
      *(uint2*)&vto[(((size_t)b * HH + h) * DD + d) * SS + s0 + srow] = pk;
    }
  }
}

// ---------------------------------------------------------------------------
// Kernel 4: MFMA flash attention, 32x32x16, swapped S^T = K·Q^T, LDS-staged
// (r7 structure) with QBLK=256: 4 waves x 64 q-rows (2 sub-blocks of 32).
// K frags are loaded LDS->reg ONCE and reused by both q-sub-blocks; V frags
// shared by both PV accumulators -> LDS traffic per FLOP halves vs r7.
// Grid 256 = 1 block/CU, XCD-chunked. Double-buffered, 1 barrier/iter.
// ---------------------------------------------------------------------------
__global__ __launch_bounds__(256, 1) void attn_mfma(
    const ushort* __restrict__ q, const ushort* __restrict__ k,
    const ushort* __restrict__ vt, ushort* __restrict__ o) {
  __shared__ __align__(16) ushort Ks[2][64 * 72];
  __shared__ __align__(16) ushort Vts[2][64 * 72];
  const int tid = threadIdx.x, w = tid >> 6, l = tid & 63;
  const int lq = l & 31, h2 = l >> 5;  // q-col / key-row-half
  // XCD swizzle: 256 blocks; blockIdx%8 = XCD -> contiguous chunk of 32 works
  const int work = ((blockIdx.x & 7) << 5) | (blockIdx.x >> 3);
  const int qt = work & 7, hb = work >> 3;
  const int h = hb & 15, b = hb >> 4;
  const int q0 = qt * 256 + w * 64;

  const size_t bh_qk = (size_t)b * SS * EE + h * DD;        // + s*EE + d
  const size_t bh_vt = (size_t)b * SS * EE + h * (DD * SS); // + d*SS + s

  const int sr0 = tid >> 3;            // 0..31
  const int se0 = (tid & 7) * 8;
  // sigma: swap bits 2 and 3 of the key index (bits 0,1,4 kept)
  const int krow0 = (sr0 & 19) | ((sr0 & 4) << 1) | ((sr0 & 8) >> 1);

  // prologue: stage tile 0
  {
    bf16x8 kr0 = *(const bf16x8*)&k[bh_qk + (size_t)sr0 * EE + se0];
    bf16x8 kr1 = *(const bf16x8*)&k[bh_qk + (size_t)(sr0 + 32) * EE + se0];
    bf16x8 vr0 = *(const bf16x8*)&vt[bh_vt + (size_t)sr0 * SS + se0];
    bf16x8 vr1 = *(const bf16x8*)&vt[bh_vt + (size_t)(sr0 + 32) * SS + se0];
    *(bf16x8*)&Ks[0][krow0 * 72 + se0] = kr0;
    *(bf16x8*)&Ks[0][(krow0 + 32) * 72 + se0] = kr1;
    *(bf16x8*)&Vts[0][sr0 * 72 + se0] = vr0;
    *(bf16x8*)&Vts[0][(sr0 + 32) * 72 + se0] = vr1;
  }

  // Q B-frags: q-rows q0 + qb*32 + lq, qb in {0,1}
  bf16x8 aq[2][4];
#pragma unroll
  for (int qb = 0; qb < 2; ++qb)
#pragma unroll
    for (int db = 0; db < 4; ++db)
      aq[qb][db] = *(const bf16x8*)&q[bh_qk +
          (size_t)(q0 + qb * 32 + lq) * EE + db * 16 + h2 * 8];

  f32x16 accO[2][2];  // [qb][ct]
  float lacc[2][2];   // [qb][kb]
#pragma unroll
  for (int qb = 0; qb < 2; ++qb) {
    lacc[qb][0] = 0.f;
    lacc[qb][1] = 0.f;
#pragma unroll
    for (int ct = 0; ct < 2; ++ct)
#pragma unroll
      for (int r = 0; r < 16; ++r) accO[qb][ct][r] = 0.f;
  }

  __syncthreads();

  for (int t = 0; t < 32; ++t) {
    const int cur = t & 1;
    bf16x8 kr0, kr1, vr0, vr1;
    if (t < 31) {  // issue next tile's loads; latency hides under compute
      const size_t kb2 = bh_qk + (size_t)((t + 1) * 64) * EE;
      kr0 = *(const bf16x8*)&k[kb2 + (size_t)sr0 * EE + se0];
      kr1 = *(const bf16x8*)&k[kb2 + (size_t)(sr0 + 32) * EE + se0];
      const size_t vb2 = bh_vt + (t + 1) * 64;
      vr0 = *(const bf16x8*)&vt[vb2 + (size_t)sr0 * SS + se0];
      vr1 = *(const bf16x8*)&vt[vb2 + (size_t)(sr0 + 32) * SS + se0];
    }

    // K frags LDS->reg once; reused by both q-sub-blocks
    bf16x8 kf[2][4];
#pragma unroll
    for (int kb = 0; kb < 2; ++kb)
#pragma unroll
      for (int db = 0; db < 4; ++db)
        kf[kb][db] = *(bf16x8*)&Ks[cur][(kb * 32 + lq) * 72 + db * 16 + h2 * 8];

    // qb0: S^T then softmax (frees s regs before qb1)
    u32x4 pwv[2][2][2];  // [qb][kb][t16]
#pragma unroll
    for (int qb = 0; qb < 2; ++qb) {
      f32x16 s[2];
      __builtin_amdgcn_s_setprio(1);
#pragma unroll
      for (int kb = 0; kb < 2; ++kb) {
        f32x16 acc;
#pragma unroll
        for (int r = 0; r < 16; ++r) acc[r] = 0.f;
#pragma unroll
        for (int db = 0; db < 4; ++db)
          acc = __builtin_amdgcn_mfma_f32_32x32x16_bf16(kf[kb][db], aq[qb][db],
                                                        acc, 0, 0, 0);
        s[kb] = acc;
      }
      __builtin_amdgcn_s_setprio(0);
#pragma unroll
      for (int kb = 0; kb < 2; ++kb)
#pragma unroll
        for (int t16 = 0; t16 < 2; ++t16)
#pragma unroll
          for (int j2 = 0; j2 < 4; ++j2) {
            float pa = __builtin_amdgcn_exp2f(s[kb][t16 * 8 + j2 * 2]);
            float pb = __builtin_amdgcn_exp2f(s[kb][t16 * 8 + j2 * 2 + 1]);
            lacc[qb][kb] += pa + pb;
            pwv[qb][kb][t16][j2] = cvt_pk(pa, pb);
          }
    }

    // V frags LDS->reg once; shared by both PV accumulators
    bf16x8 vf[2][4];  // [ct][kb*2+t16]
#pragma unroll
    for (int ct = 0; ct < 2; ++ct)
#pragma unroll
      for (int kb = 0; kb < 2; ++kb)
#pragma unroll
        for (int t16 = 0; t16 < 2; ++t16)
          vf[ct][kb * 2 + t16] = *(bf16x8*)&Vts[cur][(ct * 32 + lq) * 72 +
                                                     kb * 32 + t16 * 16 + h2 * 8];

    // O^T += V^T P^T for both q-sub-blocks
    __builtin_amdgcn_s_setprio(1);
#pragma unroll
    for (int ct = 0; ct < 2; ++ct)
#pragma unroll
      for (int kb = 0; kb < 2; ++kb)
#pragma unroll
        for (int t16 = 0; t16 < 2; ++t16) {
          accO[0][ct] = __builtin_amdgcn_mfma_f32_32x32x16_bf16(
              vf[ct][kb * 2 + t16],
              __builtin_bit_cast(bf16x8, pwv[0][kb][t16]), accO[0][ct], 0, 0, 0);
          accO[1][ct] = __builtin_amdgcn_mfma_f32_32x32x16_bf16(
              vf[ct][kb * 2 + t16],
              __builtin_bit_cast(bf16x8, pwv[1][kb][t16]), accO[1][ct], 0, 0, 0);
        }
    __builtin_amdgcn_s_setprio(0);

    // write next tile into the other buffer (vmcnt hidden under compute)
    if (t < 31) {
      const int nxt = cur ^ 1;
      *(bf16x8*)&Ks[nxt][krow0 * 72 + se0] = kr0;
      *(bf16x8*)&Ks[nxt][(krow0 + 32) * 72 + se0] = kr1;
      *(bf16x8*)&Vts[nxt][sr0 * 72 + se0] = vr0;
      *(bf16x8*)&Vts[nxt][(sr0 + 32) * 72 + se0] = vr1;
    }
    __syncthreads();
  }

  // normalize: wave halves hold complementary key sums for the same q
#pragma unroll
  for (int qb = 0; qb < 2; ++qb) {
    float tsum = lacc[qb][0] + lacc[qb][1];
    tsum += __shfl_xor(tsum, 32, 64);
    float inv = 1.f / tsum;
    size_t row = (size_t)b * SS + q0 + qb * 32 + lq;
#pragma unroll
    for (int ct = 0; ct < 2; ++ct)
#pragma unroll
      for (int rq = 0; rq < 4; ++rq) {
        uint2 pk;
        pk.x = cvt_pk(accO[qb][ct][rq * 4 + 0] * inv,
                      accO[qb][ct][rq * 4 + 1] * inv);
        pk.y = cvt_pk(accO[qb][ct][rq * 4 + 2] * inv,
                      accO[qb][ct][rq * 4 + 3] * inv);
        *(uint2*)&o[row * EE + h * DD + ct * 32 + rq * 8 + h2 * 4] = pk;
      }
  }
}

// ---------------------------------------------------------------------------
// Kernel 5: output projection, bf16 MFMA GEMM, 128x64 tile, reg-staged
// double-buffer, 1 barrier per K-step.
// ---------------------------------------------------------------------------
__global__ __launch_bounds__(256) void out_proj_mfma(
    const ushort* __restrict__ a, const ushort* __restrict__ wo,
    const float* __restrict__ bias, float* __restrict__ y) {
  __shared__ __align__(16) ushort As[2][128 * 72];
  __shared__ __align__(16) ushort Ws[2][64 * 72];
  const int tid = threadIdx.x, w = tid >> 6, l = tid & 63;
  const int g = l >> 4, c = l & 15;
  const int m0 = blockIdx.x * 128, n0 = blockIdx.y * 64;
  const int sr = tid >> 3, se = (tid & 7) * 8;

  f32x4 acc[2][4];
#pragma unroll
  for (int mf = 0; mf < 2; ++mf)
#pragma unroll
    for (int ct = 0; ct < 4; ++ct) acc[mf][ct] = (f32x4){0.f, 0.f, 0.f, 0.f};

  {
#pragma unroll
    for (int j = 0; j < 4; ++j) {
      int r = sr + j * 32;
      *(bf16x8*)&As[0][r * 72 + se] = *(const bf16x8*)&a[(size_t)(m0 + r) * EE + se];
    }
#pragma unroll
    for (int j = 0; j < 2; ++j) {
      int r = sr + j * 32;
      *(bf16x8*)&Ws[0][r * 72 + se] = *(const bf16x8*)&wo[(size_t)(n0 + r) * EE + se];
    }
  }
  __syncthreads();

  for (int t = 0; t < 16; ++t) {
    const int cur = t & 1;
    bf16x8 Arg[4], Brg[2];
    if (t < 15) {
      const int k0 = (t + 1) * 64;
#pragma unroll
      for (int j = 0; j < 4; ++j) {
        int r = sr + j * 32;
        Arg[j] = *(const bf16x8*)&a[(size_t)(m0 + r) * EE + k0 + se];
      }
#pragma unroll
      for (int j = 0; j < 2; ++j) {
        int r = sr + j * 32;
        Brg[j] = *(const bf16x8*)&wo[(size_t)(n0 + r) * EE + k0 + se];
      }
    }

    bf16x8 af[2][2];
#pragma unroll
    for (int mf = 0; mf < 2; ++mf) {
      af[mf][0] = *(bf16x8*)&As[cur][(w * 32 + mf * 16 + c) * 72 + g * 8];
      af[mf][1] = *(bf16x8*)&As[cur][(w * 32 + mf * 16 + c) * 72 + 32 + g * 8];
    }
    __builtin_amdgcn_s_setprio(1);
#pragma unroll
    for (int ct = 0; ct < 4; ++ct) {
      bf16x8 b0 = *(bf16x8*)&Ws[cur][(ct * 16 + c) * 72 + g * 8];
      bf16x8 b1 = *(bf16x8*)&Ws[cur][(ct * 16 + c) * 72 + 32 + g * 8];
#pragma unroll
      for (int mf = 0; mf < 2; ++mf) {
        acc[mf][ct] = __builtin_amdgcn_mfma_f32_16x16x32_bf16(af[mf][0], b0, acc[mf][ct], 0, 0, 0);
        acc[mf][ct] = __builtin_amdgcn_mfma_f32_16x16x32_bf16(af[mf][1], b1, acc[mf][ct], 0, 0, 0);
      }
    }
    __builtin_amdgcn_s_setprio(0);

    if (t < 15) {
      const int nxt = cur ^ 1;
#pragma unroll
      for (int j = 0; j < 4; ++j) {
        int r = sr + j * 32;
        *(bf16x8*)&As[nxt][r * 72 + se] = Arg[j];
      }
#pragma unroll
      for (int j = 0; j < 2; ++j) {
        int r = sr + j * 32;
        *(bf16x8*)&Ws[nxt][r * 72 + se] = Brg[j];
      }
    }
    __syncthreads();
  }

#pragma unroll
  for (int ct = 0; ct < 4; ++ct) {
    float bv = bias[n0 + ct * 16 + c];
#pragma unroll
    for (int mf = 0; mf < 2; ++mf)
#pragma unroll
      for (int r = 0; r < 4; ++r)
        y[(size_t)(m0 + w * 32 + mf * 16 + g * 4 + r) * EE + n0 + ct * 16 + c] =
            acc[mf][ct][r] + bv;
  }
}

// ---------------------------------------------------------------------------
extern "C" void kernel_launch(void* const* d_in, const int* in_sizes, int n_in,
                              void* d_out, int out_size, void* d_ws,
                              size_t ws_size, hipStream_t stream) {
  const float* x = (const float*)d_in[0];
  const float* Wq = (const float*)d_in[1];
  const float* Wk = (const float*)d_in[2];
  const float* Wv = (const float*)d_in[3];
  const float* Wo = (const float*)d_in[4];
  const float* bo = (const float*)d_in[5];
  float* out = (float*)d_out;

  const size_t per = (size_t)NROWS * 64;  // 4,194,304 elems
  ushort* qb = (ushort*)d_ws;                       //  8 MB
  ushort* kb = qb + per;                            //  8 MB
  ushort* vtb = kb + per;                           //  8 MB
  ushort* aob = vtb + per;                          //  8 MB
  ushort* wob = aob + per;                          //  2 MB
  ushort* wqkvb = wob + 1024 * 1024;                // 24 KB

  wconv<<<518, 256, 0, stream>>>(Wq, Wk, Wv, Wo, wqkvb, wob);
  qkv_mfma<<<dim3(16, 16, 2), 256, 0, stream>>>(x, wqkvb, qb, kb, vtb);
  attn_mfma<<<256, 256, 0, stream>>>(qb, kb, vtb, aob);
  out_proj_mfma<<<dim3(32, 16), 256, 0, stream>>>(aob, wob, bo, out);
}

// Round 11
// 81.507 us; speedup vs baseline: 1.9662x; 1.0728x over previous
//
#include <hip/hip_runtime.h>
#include <math.h>

#define BB 2
#define SS 2048
#define EE 1024
#define HH 16
#define DD 64
constexpr int NROWS = BB * SS * HH;   // 65536 rows of D=64
// q pre-scale: (1/sqrt(E)) * log2(e) so attention can use exp2 directly
constexpr float SCALE_Q = 1.4426950408889634f / 32.0f;

typedef __attribute__((ext_vector_type(8))) short bf16x8;
typedef __attribute__((ext_vector_type(4))) float f32x4;
typedef __attribute__((ext_vector_type(16))) float f32x16;
typedef __attribute__((ext_vector_type(4))) unsigned u32x4;

__device__ inline ushort f2bf(float f) {
  unsigned u = __builtin_bit_cast(unsigned, f);
  u += 0x7fffu + ((u >> 16) & 1u);   // RNE
  return (ushort)(u >> 16);
}

// packed f32x2 -> bf16x2 (RNE), one VALU inst
__device__ inline unsigned cvt_pk(float lo, float hi) {
  unsigned r;
  asm("v_cvt_pk_bf16_f32 %0, %1, %2" : "=v"(r) : "v"(lo), "v"(hi));
  return r;
}

// ---------------------------------------------------------------------------
// Kernel 0: all weight converts in ONE launch.
// ---------------------------------------------------------------------------
__global__ __launch_bounds__(256) void wconv(
    const float* __restrict__ Wq, const float* __restrict__ Wk,
    const float* __restrict__ Wv, const float* __restrict__ Wo,
    ushort* __restrict__ wqkvb, ushort* __restrict__ wob) {
  int idx = blockIdx.x * 256 + threadIdx.x;  // grid 518 * 256 = 132608
  const float* sp;
  ushort* dp;
  if (idx < 1536) {
    int t = idx >> 9, j = idx & 511;
    const float* W = (t == 0) ? Wq : ((t == 1) ? Wk : Wv);
    sp = W + j * 8;
    dp = wqkvb + t * 4096 + j * 8;
  } else {
    size_t j = (size_t)(idx - 1536) * 8;
    sp = Wo + j;
    dp = wob + j;
  }
  float4 a = *(const float4*)sp;
  float4 c = *(const float4*)(sp + 4);
  u32x4 r;
  r[0] = cvt_pk(a.x, a.y);
  r[1] = cvt_pk(a.z, a.w);
  r[2] = cvt_pk(c.x, c.y);
  r[3] = cvt_pk(c.z, c.w);
  *(u32x4*)dp = r;
}

// ---------------------------------------------------------------------------
// Kernel 1: QKV projection, h-major blocks (fixed b,h; 128 s-rows).
// q,k written [B,S,H,D]; V written TRANSPOSED [B,H,D,S] directly.
// ---------------------------------------------------------------------------
__global__ __launch_bounds__(256) void qkv_mfma(
    const float* __restrict__ x, const ushort* __restrict__ wqkv,
    ushort* __restrict__ qo, ushort* __restrict__ ko, ushort* __restrict__ vto) {
  __shared__ __align__(16) ushort Xs[128 * 72];
  __shared__ __align__(16) ushort Ws[3][64 * 72];
  const int tid = threadIdx.x, w = tid >> 6, l = tid & 63;
  const int g = l >> 4, c = l & 15;
  const int s0 = blockIdx.x * 128, h = blockIdx.y, b = blockIdx.z;

  for (int i = tid; i < 1536; i += 256) {
    int t = i >> 9, j = i & 511;
    int r = j >> 3, e0 = (j & 7) * 8;
    *(bf16x8*)&Ws[t][r * 72 + e0] = *(const bf16x8*)&wqkv[t * 4096 + r * 64 + e0];
  }
  for (int i = tid; i < 2048; i += 256) {
    int r = i >> 4, c4 = (i & 15) * 4;
    float4 xv = *(const float4*)&x[(((size_t)b * SS + s0 + r) * HH + h) * DD + c4];
    uint2 pk;
    pk.x = cvt_pk(xv.x, xv.y);
    pk.y = cvt_pk(xv.z, xv.w);
    *(uint2*)&Xs[r * 72 + c4] = pk;
  }
  __syncthreads();

  bf16x8 a_[2][2];
#pragma unroll
  for (int rf = 0; rf < 2; ++rf) {
    a_[rf][0] = *(bf16x8*)&Xs[(w * 32 + rf * 16 + c) * 72 + g * 8];
    a_[rf][1] = *(bf16x8*)&Xs[(w * 32 + rf * 16 + c) * 72 + 32 + g * 8];
  }

  // q and k: row-major [B,S,H,D]
#pragma unroll
  for (int t = 0; t < 2; ++t) {
    ushort* out = (t == 0) ? qo : ko;
    const float sc = (t == 0) ? SCALE_Q : 1.0f;
#pragma unroll
    for (int ct = 0; ct < 4; ++ct) {
      bf16x8 b0 = *(bf16x8*)&Ws[t][(ct * 16 + c) * 72 + g * 8];
      bf16x8 b1 = *(bf16x8*)&Ws[t][(ct * 16 + c) * 72 + 32 + g * 8];
#pragma unroll
      for (int rf = 0; rf < 2; ++rf) {
        f32x4 acc = (f32x4){0.f, 0.f, 0.f, 0.f};
        acc = __builtin_amdgcn_mfma_f32_16x16x32_bf16(a_[rf][0], b0, acc, 0, 0, 0);
        acc = __builtin_amdgcn_mfma_f32_16x16x32_bf16(a_[rf][1], b1, acc, 0, 0, 0);
#pragma unroll
        for (int r = 0; r < 4; ++r) {
          int srow = w * 32 + rf * 16 + g * 4 + r;
          out[(((size_t)b * SS + s0 + srow) * HH + h) * DD + ct * 16 + c] =
              f2bf(acc[r] * sc);
        }
      }
    }
  }
  // v: transposed [B,H,D,S], packed 8B stores
#pragma unroll
  for (int ct = 0; ct < 4; ++ct) {
    bf16x8 b0 = *(bf16x8*)&Ws[2][(ct * 16 + c) * 72 + g * 8];
    bf16x8 b1 = *(bf16x8*)&Ws[2][(ct * 16 + c) * 72 + 32 + g * 8];
#pragma unroll
    for (int rf = 0; rf < 2; ++rf) {
      f32x4 acc = (f32x4){0.f, 0.f, 0.f, 0.f};
      acc = __builtin_amdgcn_mfma_f32_16x16x32_bf16(a_[rf][0], b0, acc, 0, 0, 0);
      acc = __builtin_amdgcn_mfma_f32_16x16x32_bf16(a_[rf][1], b1, acc, 0, 0, 0);
      uint2 pk;
      pk.x = cvt_pk(acc[0], acc[1]);
      pk.y = cvt_pk(acc[2], acc[3]);
      int d = ct * 16 + c;
      int srow = w * 32 + rf * 16 + g * 4;
      *(uint2*)&vto[(((size_t)b * HH + h) * DD + d) * SS + s0 + srow] = pk;
    }
  }
}

// ---------------------------------------------------------------------------
// Kernel 4: MFMA flash attention, 32x32x16, swapped S^T = K·Q^T, software-
// pipelined softmax: PV of tile t-1 runs INTERLEAVED with exp of tile t
// (independent -> VALU exp hides under PV MFMAs). V frags for tile t are
// captured to regs in iter t; pwv carried one iter. No setprio (lockstep
// structure -> let the scheduler interleave freely).
// QBLK=128 (4 waves x 32 q), KVBLK=64, dbuf, 1 barrier/iter, 512 blocks.
// ---------------------------------------------------------------------------
__global__ __launch_bounds__(256) void attn_mfma(
    const ushort* __restrict__ q, const ushort* __restrict__ k,
    const ushort* __restrict__ vt, ushort* __restrict__ o) {
  __shared__ __align__(16) ushort Ks[2][64 * 72];
  __shared__ __align__(16) ushort Vts[2][64 * 72];
  const int tid = threadIdx.x, w = tid >> 6, l = tid & 63;
  const int lq = l & 31, h2 = l >> 5;  // q-col / key-row-half
  // XCD swizzle: blockIdx%8 = XCD -> contiguous chunk of 64 works
  const int work = ((blockIdx.x & 7) << 6) | (blockIdx.x >> 3);
  const int qt = work & 15, hb = work >> 4;
  const int h = hb & 15, b = hb >> 4;
  const int q0 = qt * 128 + w * 32;

  const size_t bh_qk = (size_t)b * SS * EE + h * DD;        // + s*EE + d
  const size_t bh_vt = (size_t)b * SS * EE + h * (DD * SS); // + d*SS + s

  const int sr0 = tid >> 3;            // 0..31
  const int se0 = (tid & 7) * 8;
  // sigma: swap bits 2 and 3 of the key index (bits 0,1,4 kept)
  const int krow0 = (sr0 & 19) | ((sr0 & 4) << 1) | ((sr0 & 8) >> 1);

  // prologue: stage tile 0
  {
    bf16x8 kr0 = *(const bf16x8*)&k[bh_qk + (size_t)sr0 * EE + se0];
    bf16x8 kr1 = *(const bf16x8*)&k[bh_qk + (size_t)(sr0 + 32) * EE + se0];
    bf16x8 vr0 = *(const bf16x8*)&vt[bh_vt + (size_t)sr0 * SS + se0];
    bf16x8 vr1 = *(const bf16x8*)&vt[bh_vt + (size_t)(sr0 + 32) * SS + se0];
    *(bf16x8*)&Ks[0][krow0 * 72 + se0] = kr0;
    *(bf16x8*)&Ks[0][(krow0 + 32) * 72 + se0] = kr1;
    *(bf16x8*)&Vts[0][sr0 * 72 + se0] = vr0;
    *(bf16x8*)&Vts[0][(sr0 + 32) * 72 + se0] = vr1;
  }

  // Q B-frags: lane's q-row = q0 + lq
  bf16x8 aq[4];
#pragma unroll
  for (int db = 0; db < 4; ++db)
    aq[db] = *(const bf16x8*)&q[bh_qk + (size_t)(q0 + lq) * EE + db * 16 + h2 * 8];

  f32x16 accO[2];
  float lacc[2] = {0.f, 0.f};
#pragma unroll
  for (int ct = 0; ct < 2; ++ct)
#pragma unroll
    for (int r = 0; r < 16; ++r) accO[ct][r] = 0.f;

  u32x4 pwvP[2][2];   // previous tile's P (PV operands)
  bf16x8 vfP[2][4];   // previous tile's V frags [ct][kb*2+t16]

  __syncthreads();

  // ---- iter 0 (peeled: QK+exp only, capture V frags; no PV) ----
  {
    bf16x8 kr0 = *(const bf16x8*)&k[bh_qk + (size_t)(64 + sr0) * EE + se0];
    bf16x8 kr1 = *(const bf16x8*)&k[bh_qk + (size_t)(64 + sr0 + 32) * EE + se0];
    bf16x8 vr0 = *(const bf16x8*)&vt[bh_vt + 64 + (size_t)sr0 * SS + se0];
    bf16x8 vr1 = *(const bf16x8*)&vt[bh_vt + 64 + (size_t)(sr0 + 32) * SS + se0];

    f32x16 s[2];
#pragma unroll
    for (int kb = 0; kb < 2; ++kb) {
      f32x16 acc;
#pragma unroll
      for (int r = 0; r < 16; ++r) acc[r] = 0.f;
#pragma unroll
      for (int db = 0; db < 4; ++db) {
        bf16x8 ka = *(bf16x8*)&Ks[0][(kb * 32 + lq) * 72 + db * 16 + h2 * 8];
        acc = __builtin_amdgcn_mfma_f32_32x32x16_bf16(ka, aq[db], acc, 0, 0, 0);
      }
      s[kb] = acc;
    }
#pragma unroll
    for (int kb = 0; kb < 2; ++kb)
#pragma unroll
      for (int t16 = 0; t16 < 2; ++t16)
#pragma unroll
        for (int j2 = 0; j2 < 4; ++j2) {
          float pa = __builtin_amdgcn_exp2f(s[kb][t16 * 8 + j2 * 2]);
          float pb = __builtin_amdgcn_exp2f(s[kb][t16 * 8 + j2 * 2 + 1]);
          lacc[kb] += pa + pb;
          pwvP[kb][t16][j2] = cvt_pk(pa, pb);
        }
#pragma unroll
    for (int ct = 0; ct < 2; ++ct)
#pragma unroll
      for (int kb = 0; kb < 2; ++kb)
#pragma unroll
        for (int t16 = 0; t16 < 2; ++t16)
          vfP[ct][kb * 2 + t16] = *(bf16x8*)&Vts[0][(ct * 32 + lq) * 72 +
                                                    kb * 32 + t16 * 16 + h2 * 8];
    *(bf16x8*)&Ks[1][krow0 * 72 + se0] = kr0;
    *(bf16x8*)&Ks[1][(krow0 + 32) * 72 + se0] = kr1;
    *(bf16x8*)&Vts[1][sr0 * 72 + se0] = vr0;
    *(bf16x8*)&Vts[1][(sr0 + 32) * 72 + se0] = vr1;
    __syncthreads();
  }

  // ---- main loop: iter t computes QK(t), exp(t) || PV(t-1) ----
  for (int t = 1; t < 32; ++t) {
    const int cur = t & 1;
    const int tn = (t + 1) & 31;  // wraps to 0 at t=31 (harmless extra stage)

    bf16x8 kr0, kr1, vr0, vr1;
    {
      const size_t kb2 = bh_qk + (size_t)(tn * 64) * EE;
      kr0 = *(const bf16x8*)&k[kb2 + (size_t)sr0 * EE + se0];
      kr1 = *(const bf16x8*)&k[kb2 + (size_t)(sr0 + 32) * EE + se0];
      const size_t vb2 = bh_vt + tn * 64;
      vr0 = *(const bf16x8*)&vt[vb2 + (size_t)sr0 * SS + se0];
      vr1 = *(const bf16x8*)&vt[vb2 + (size_t)(sr0 + 32) * SS + se0];
    }

    // QK(t)
    f32x16 s[2];
#pragma unroll
    for (int kb = 0; kb < 2; ++kb) {
      f32x16 acc;
#pragma unroll
      for (int r = 0; r < 16; ++r) acc[r] = 0.f;
#pragma unroll
      for (int db = 0; db < 4; ++db) {
        bf16x8 ka = *(bf16x8*)&Ks[cur][(kb * 32 + lq) * 72 + db * 16 + h2 * 8];
        acc = __builtin_amdgcn_mfma_f32_32x32x16_bf16(ka, aq[db], acc, 0, 0, 0);
      }
      s[kb] = acc;
    }

    // PV(t-1) [MFMA] -- independent of exp(t) [VALU]: scheduler interleaves
#pragma unroll
    for (int ct = 0; ct < 2; ++ct)
#pragma unroll
      for (int kb = 0; kb < 2; ++kb)
#pragma unroll
        for (int t16 = 0; t16 < 2; ++t16)
          accO[ct] = __builtin_amdgcn_mfma_f32_32x32x16_bf16(
              vfP[ct][kb * 2 + t16],
              __builtin_bit_cast(bf16x8, pwvP[kb][t16]), accO[ct], 0, 0, 0);

    // exp(t)
    u32x4 pwvC[2][2];
#pragma unroll
    for (int kb = 0; kb < 2; ++kb)
#pragma unroll
      for (int t16 = 0; t16 < 2; ++t16)
#pragma unroll
        for (int j2 = 0; j2 < 4; ++j2) {
          float pa = __builtin_amdgcn_exp2f(s[kb][t16 * 8 + j2 * 2]);
          float pb = __builtin_amdgcn_exp2f(s[kb][t16 * 8 + j2 * 2 + 1]);
          lacc[kb] += pa + pb;
          pwvC[kb][t16][j2] = cvt_pk(pa, pb);
        }

    // capture V(t) frags to regs (PV(t) runs next iter)
#pragma unroll
    for (int ct = 0; ct < 2; ++ct)
#pragma unroll
      for (int kb = 0; kb < 2; ++kb)
#pragma unroll
        for (int t16 = 0; t16 < 2; ++t16)
          vfP[ct][kb * 2 + t16] = *(bf16x8*)&Vts[cur][(ct * 32 + lq) * 72 +
                                                      kb * 32 + t16 * 16 + h2 * 8];

    // stage tile tn into the other buffer
    {
      const int nxt = cur ^ 1;
      *(bf16x8*)&Ks[nxt][krow0 * 72 + se0] = kr0;
      *(bf16x8*)&Ks[nxt][(krow0 + 32) * 72 + se0] = kr1;
      *(bf16x8*)&Vts[nxt][sr0 * 72 + se0] = vr0;
      *(bf16x8*)&Vts[nxt][(sr0 + 32) * 72 + se0] = vr1;
    }
    __syncthreads();

#pragma unroll
    for (int kb = 0; kb < 2; ++kb)
#pragma unroll
      for (int t16 = 0; t16 < 2; ++t16) pwvP[kb][t16] = pwvC[kb][t16];
  }

  // epilogue: PV(31)
#pragma unroll
  for (int ct = 0; ct < 2; ++ct)
#pragma unroll
    for (int kb = 0; kb < 2; ++kb)
#pragma unroll
      for (int t16 = 0; t16 < 2; ++t16)
        accO[ct] = __builtin_amdgcn_mfma_f32_32x32x16_bf16(
            vfP[ct][kb * 2 + t16],
            __builtin_bit_cast(bf16x8, pwvP[kb][t16]), accO[ct], 0, 0, 0);

  // normalize: wave halves hold complementary key sums for the same q
  {
    float tsum = lacc[0] + lacc[1];
    tsum += __shfl_xor(tsum, 32, 64);
    float inv = 1.f / tsum;
    size_t row = (size_t)b * SS + q0 + lq;
#pragma unroll
    for (int ct = 0; ct < 2; ++ct)
#pragma unroll
      for (int rq = 0; rq < 4; ++rq) {
        uint2 pk;
        pk.x = cvt_pk(accO[ct][rq * 4 + 0] * inv, accO[ct][rq * 4 + 1] * inv);
        pk.y = cvt_pk(accO[ct][rq * 4 + 2] * inv, accO[ct][rq * 4 + 3] * inv);
        *(uint2*)&o[row * EE + h * DD + ct * 32 + rq * 8 + h2 * 4] = pk;
      }
  }
}

// ---------------------------------------------------------------------------
// Kernel 5: output projection, bf16 MFMA GEMM, 128x64 tile, reg-staged
// double-buffer, 1 barrier per K-step.
// ---------------------------------------------------------------------------
__global__ __launch_bounds__(256) void out_proj_mfma(
    const ushort* __restrict__ a, const ushort* __restrict__ wo,
    const float* __restrict__ bias, float* __restrict__ y) {
  __shared__ __align__(16) ushort As[2][128 * 72];
  __shared__ __align__(16) ushort Ws[2][64 * 72];
  const int tid = threadIdx.x, w = tid >> 6, l = tid & 63;
  const int g = l >> 4, c = l & 15;
  const int m0 = blockIdx.x * 128, n0 = blockIdx.y * 64;
  const int sr = tid >> 3, se = (tid & 7) * 8;

  f32x4 acc[2][4];
#pragma unroll
  for (int mf = 0; mf < 2; ++mf)
#pragma unroll
    for (int ct = 0; ct < 4; ++ct) acc[mf][ct] = (f32x4){0.f, 0.f, 0.f, 0.f};

  {
#pragma unroll
    for (int j = 0; j < 4; ++j) {
      int r = sr + j * 32;
      *(bf16x8*)&As[0][r * 72 + se] = *(const bf16x8*)&a[(size_t)(m0 + r) * EE + se];
    }
#pragma unroll
    for (int j = 0; j < 2; ++j) {
      int r = sr + j * 32;
      *(bf16x8*)&Ws[0][r * 72 + se] = *(const bf16x8*)&wo[(size_t)(n0 + r) * EE + se];
    }
  }
  __syncthreads();

  for (int t = 0; t < 16; ++t) {
    const int cur = t & 1;
    bf16x8 Arg[4], Brg[2];
    if (t < 15) {
      const int k0 = (t + 1) * 64;
#pragma unroll
      for (int j = 0; j < 4; ++j) {
        int r = sr + j * 32;
        Arg[j] = *(const bf16x8*)&a[(size_t)(m0 + r) * EE + k0 + se];
      }
#pragma unroll
      for (int j = 0; j < 2; ++j) {
        int r = sr + j * 32;
        Brg[j] = *(const bf16x8*)&wo[(size_t)(n0 + r) * EE + k0 + se];
      }
    }

    bf16x8 af[2][2];
#pragma unroll
    for (int mf = 0; mf < 2; ++mf) {
      af[mf][0] = *(bf16x8*)&As[cur][(w * 32 + mf * 16 + c) * 72 + g * 8];
      af[mf][1] = *(bf16x8*)&As[cur][(w * 32 + mf * 16 + c) * 72 + 32 + g * 8];
    }
    __builtin_amdgcn_s_setprio(1);
#pragma unroll
    for (int ct = 0; ct < 4; ++ct) {
      bf16x8 b0 = *(bf16x8*)&Ws[cur][(ct * 16 + c) * 72 + g * 8];
      bf16x8 b1 = *(bf16x8*)&Ws[cur][(ct * 16 + c) * 72 + 32 + g * 8];
#pragma unroll
      for (int mf = 0; mf < 2; ++mf) {
        acc[mf][ct] = __builtin_amdgcn_mfma_f32_16x16x32_bf16(af[mf][0], b0, acc[mf][ct], 0, 0, 0);
        acc[mf][ct] = __builtin_amdgcn_mfma_f32_16x16x32_bf16(af[mf][1], b1, acc[mf][ct], 0, 0, 0);
      }
    }
    __builtin_amdgcn_s_setprio(0);

    if (t < 15) {
      const int nxt = cur ^ 1;
#pragma unroll
      for (int j = 0; j < 4; ++j) {
        int r = sr + j * 32;
        *(bf16x8*)&As[nxt][r * 72 + se] = Arg[j];
      }
#pragma unroll
      for (int j = 0; j < 2; ++j) {
        int r = sr + j * 32;
        *(bf16x8*)&Ws[nxt][r * 72 + se] = Brg[j];
      }
    }
    __syncthreads();
  }

#pragma unroll
  for (int ct = 0; ct < 4; ++ct) {
    float bv = bias[n0 + ct * 16 + c];
#pragma unroll
    for (int mf = 0; mf < 2; ++mf)
#pragma unroll
      for (int r = 0; r < 4; ++r)
        y[(size_t)(m0 + w * 32 + mf * 16 + g * 4 + r) * EE + n0 + ct * 16 + c] =
            acc[mf][ct][r] + bv;
  }
}

// ---------------------------------------------------------------------------
extern "C" void kernel_launch(void* const* d_in, const int* in_sizes, int n_in,
                              void* d_out, int out_size, void* d_ws,
                              size_t ws_size, hipStream_t stream) {
  const float* x = (const float*)d_in[0];
  const float* Wq = (const float*)d_in[1];
  const float* Wk = (const float*)d_in[2];
  const float* Wv = (const float*)d_in[3];
  const float* Wo = (const float*)d_in[4];
  const float* bo = (const float*)d_in[5];
  float* out = (float*)d_out;

  const size_t per = (size_t)NROWS * 64;  // 4,194,304 elems
  ushort* qb = (ushort*)d_ws;                       //  8 MB
  ushort* kb = qb + per;                            //  8 MB
  ushort* vtb = kb + per;                           //  8 MB
  ushort* aob = vtb + per;                          //  8 MB
  ushort* wob = aob + per;                          //  2 MB
  ushort* wqkvb = wob + 1024 * 1024;                // 24 KB

  wconv<<<518, 256, 0, stream>>>(Wq, Wk, Wv, Wo, wqkvb, wob);
  qkv_mfma<<<dim3(16, 16, 2), 256, 0, stream>>>(x, wqkvb, qb, kb, vtb);
  attn_mfma<<<512, 256, 0, stream>>>(qb, kb, vtb, aob);
  out_proj_mfma<<<dim3(32, 16), 256, 0, stream>>>(aob, wob, bo, out);
}

// Round 12
// 81.292 us; speedup vs baseline: 1.9714x; 1.0026x over previous
//
#include <hip/hip_runtime.h>
#include <math.h>

#define BB 2
#define SS 2048
#define EE 1024
#define HH 16
#define DD 64
constexpr int NROWS = BB * SS * HH;   // 65536 rows of D=64
// q pre-scale: (1/sqrt(E)) * log2(e) so attention can use exp2 directly
constexpr float SCALE_Q = 1.4426950408889634f / 32.0f;

typedef __attribute__((ext_vector_type(8))) short bf16x8;
typedef __attribute__((ext_vector_type(4))) float f32x4;
typedef __attribute__((ext_vector_type(16))) float f32x16;
typedef __attribute__((ext_vector_type(4))) unsigned u32x4;

__device__ inline ushort f2bf(float f) {
  unsigned u = __builtin_bit_cast(unsigned, f);
  u += 0x7fffu + ((u >> 16) & 1u);   // RNE
  return (ushort)(u >> 16);
}

// packed f32x2 -> bf16x2 (RNE), one VALU inst
__device__ inline unsigned cvt_pk(float lo, float hi) {
  unsigned r;
  asm("v_cvt_pk_bf16_f32 %0, %1, %2" : "=v"(r) : "v"(lo), "v"(hi));
  return r;
}

// ---------------------------------------------------------------------------
// Kernel 0: all weight converts in ONE launch.
// ---------------------------------------------------------------------------
__global__ __launch_bounds__(256) void wconv(
    const float* __restrict__ Wq, const float* __restrict__ Wk,
    const float* __restrict__ Wv, const float* __restrict__ Wo,
    ushort* __restrict__ wqkvb, ushort* __restrict__ wob) {
  int idx = blockIdx.x * 256 + threadIdx.x;  // grid 518 * 256 = 132608
  const float* sp;
  ushort* dp;
  if (idx < 1536) {
    int t = idx >> 9, j = idx & 511;
    const float* W = (t == 0) ? Wq : ((t == 1) ? Wk : Wv);
    sp = W + j * 8;
    dp = wqkvb + t * 4096 + j * 8;
  } else {
    size_t j = (size_t)(idx - 1536) * 8;
    sp = Wo + j;
    dp = wob + j;
  }
  float4 a = *(const float4*)sp;
  float4 c = *(const float4*)(sp + 4);
  u32x4 r;
  r[0] = cvt_pk(a.x, a.y);
  r[1] = cvt_pk(a.z, a.w);
  r[2] = cvt_pk(c.x, c.y);
  r[3] = cvt_pk(c.z, c.w);
  *(u32x4*)dp = r;
}

// ---------------------------------------------------------------------------
// Kernel 1: QKV projection, h-major blocks (fixed b,h; 128 s-rows).
// q,k use SWAPPED operands (A=W, B=X): C-layout gives lane 4 consecutive
// d-elems of one s-row -> packed uint2 stores (was 64 scalar stores).
// V written TRANSPOSED [B,H,D,S] via the unswapped form (4 consecutive s).
// ---------------------------------------------------------------------------
__global__ __launch_bounds__(256) void qkv_mfma(
    const float* __restrict__ x, const ushort* __restrict__ wqkv,
    ushort* __restrict__ qo, ushort* __restrict__ ko, ushort* __restrict__ vto) {
  __shared__ __align__(16) ushort Xs[128 * 72];
  __shared__ __align__(16) ushort Ws[3][64 * 72];
  const int tid = threadIdx.x, w = tid >> 6, l = tid & 63;
  const int g = l >> 4, c = l & 15;
  const int s0 = blockIdx.x * 128, h = blockIdx.y, b = blockIdx.z;

  for (int i = tid; i < 1536; i += 256) {
    int t = i >> 9, j = i & 511;
    int r = j >> 3, e0 = (j & 7) * 8;
    *(bf16x8*)&Ws[t][r * 72 + e0] = *(const bf16x8*)&wqkv[t * 4096 + r * 64 + e0];
  }
  for (int i = tid; i < 2048; i += 256) {
    int r = i >> 4, c4 = (i & 15) * 4;
    float4 xv = *(const float4*)&x[(((size_t)b * SS + s0 + r) * HH + h) * DD + c4];
    uint2 pk;
    pk.x = cvt_pk(xv.x, xv.y);
    pk.y = cvt_pk(xv.z, xv.w);
    *(uint2*)&Xs[r * 72 + c4] = pk;
  }
  __syncthreads();

  bf16x8 a_[2][2];
#pragma unroll
  for (int rf = 0; rf < 2; ++rf) {
    a_[rf][0] = *(bf16x8*)&Xs[(w * 32 + rf * 16 + c) * 72 + g * 8];
    a_[rf][1] = *(bf16x8*)&Xs[(w * 32 + rf * 16 + c) * 72 + 32 + g * 8];
  }

  // q and k: swapped operands -> D[e][s]; lane (g,c) holds s-row c,
  // e = ct*16 + g*4 + r (4 consecutive) -> packed uint2 store.
#pragma unroll
  for (int t = 0; t < 2; ++t) {
    ushort* out = (t == 0) ? qo : ko;
    const float sc = (t == 0) ? SCALE_Q : 1.0f;
#pragma unroll
    for (int ct = 0; ct < 4; ++ct) {
      bf16x8 b0 = *(bf16x8*)&Ws[t][(ct * 16 + c) * 72 + g * 8];
      bf16x8 b1 = *(bf16x8*)&Ws[t][(ct * 16 + c) * 72 + 32 + g * 8];
#pragma unroll
      for (int rf = 0; rf < 2; ++rf) {
        f32x4 acc = (f32x4){0.f, 0.f, 0.f, 0.f};
        acc = __builtin_amdgcn_mfma_f32_16x16x32_bf16(b0, a_[rf][0], acc, 0, 0, 0);
        acc = __builtin_amdgcn_mfma_f32_16x16x32_bf16(b1, a_[rf][1], acc, 0, 0, 0);
        uint2 pk;
        pk.x = cvt_pk(acc[0] * sc, acc[1] * sc);
        pk.y = cvt_pk(acc[2] * sc, acc[3] * sc);
        int srow = s0 + w * 32 + rf * 16 + c;
        *(uint2*)&out[((size_t)b * SS + srow) * EE + h * DD + ct * 16 + g * 4] = pk;
      }
    }
  }
  // v: transposed [B,H,D,S], packed 8B stores (unswapped form)
#pragma unroll
  for (int ct = 0; ct < 4; ++ct) {
    bf16x8 b0 = *(bf16x8*)&Ws[2][(ct * 16 + c) * 72 + g * 8];
    bf16x8 b1 = *(bf16x8*)&Ws[2][(ct * 16 + c) * 72 + 32 + g * 8];
#pragma unroll
    for (int rf = 0; rf < 2; ++rf) {
      f32x4 acc = (f32x4){0.f, 0.f, 0.f, 0.f};
      acc = __builtin_amdgcn_mfma_f32_16x16x32_bf16(a_[rf][0], b0, acc, 0, 0, 0);
      acc = __builtin_amdgcn_mfma_f32_16x16x32_bf16(a_[rf][1], b1, acc, 0, 0, 0);
      uint2 pk;
      pk.x = cvt_pk(acc[0], acc[1]);
      pk.y = cvt_pk(acc[2], acc[3]);
      int d = ct * 16 + c;
      int srow = w * 32 + rf * 16 + g * 4;
      *(uint2*)&vto[(((size_t)b * HH + h) * DD + d) * SS + s0 + srow] = pk;
    }
  }
}

// ---------------------------------------------------------------------------
// Kernel 4: MFMA flash attention, 32x32x16, swapped S^T = K·Q^T, software-
// pipelined softmax with PV-FIRST ordering: at barrier exit PV(t-1) has all
// operands in regs -> matrix pipe starts immediately; K ds_read latency
// hides under it; exp(t) [VALU] then overlaps trailing PV/QK scheduling.
// QBLK=128 (4 waves x 32 q), KVBLK=64, dbuf, 1 barrier/iter, 512 blocks.
// ---------------------------------------------------------------------------
__global__ __launch_bounds__(256) void attn_mfma(
    const ushort* __restrict__ q, const ushort* __restrict__ k,
    const ushort* __restrict__ vt, ushort* __restrict__ o) {
  __shared__ __align__(16) ushort Ks[2][64 * 72];
  __shared__ __align__(16) ushort Vts[2][64 * 72];
  const int tid = threadIdx.x, w = tid >> 6, l = tid & 63;
  const int lq = l & 31, h2 = l >> 5;  // q-col / key-row-half
  // XCD swizzle: blockIdx%8 = XCD -> contiguous chunk of 64 works
  const int work = ((blockIdx.x & 7) << 6) | (blockIdx.x >> 3);
  const int qt = work & 15, hb = work >> 4;
  const int h = hb & 15, b = hb >> 4;
  const int q0 = qt * 128 + w * 32;

  const size_t bh_qk = (size_t)b * SS * EE + h * DD;        // + s*EE + d
  const size_t bh_vt = (size_t)b * SS * EE + h * (DD * SS); // + d*SS + s

  const int sr0 = tid >> 3;            // 0..31
  const int se0 = (tid & 7) * 8;
  // sigma: swap bits 2 and 3 of the key index (bits 0,1,4 kept)
  const int krow0 = (sr0 & 19) | ((sr0 & 4) << 1) | ((sr0 & 8) >> 1);

  // prologue: stage tile 0
  {
    bf16x8 kr0 = *(const bf16x8*)&k[bh_qk + (size_t)sr0 * EE + se0];
    bf16x8 kr1 = *(const bf16x8*)&k[bh_qk + (size_t)(sr0 + 32) * EE + se0];
    bf16x8 vr0 = *(const bf16x8*)&vt[bh_vt + (size_t)sr0 * SS + se0];
    bf16x8 vr1 = *(const bf16x8*)&vt[bh_vt + (size_t)(sr0 + 32) * SS + se0];
    *(bf16x8*)&Ks[0][krow0 * 72 + se0] = kr0;
    *(bf16x8*)&Ks[0][(krow0 + 32) * 72 + se0] = kr1;
    *(bf16x8*)&Vts[0][sr0 * 72 + se0] = vr0;
    *(bf16x8*)&Vts[0][(sr0 + 32) * 72 + se0] = vr1;
  }

  // Q B-frags: lane's q-row = q0 + lq
  bf16x8 aq[4];
#pragma unroll
  for (int db = 0; db < 4; ++db)
    aq[db] = *(const bf16x8*)&q[bh_qk + (size_t)(q0 + lq) * EE + db * 16 + h2 * 8];

  f32x16 accO[2];
  float lacc[2] = {0.f, 0.f};
#pragma unroll
  for (int ct = 0; ct < 2; ++ct)
#pragma unroll
    for (int r = 0; r < 16; ++r) accO[ct][r] = 0.f;

  u32x4 pwvP[2][2];   // previous tile's P (PV operands)
  bf16x8 vfP[2][4];   // previous tile's V frags [ct][kb*2+t16]

  __syncthreads();

  // ---- iter 0 (peeled: QK+exp only, capture V frags; no PV) ----
  {
    bf16x8 kr0 = *(const bf16x8*)&k[bh_qk + (size_t)(64 + sr0) * EE + se0];
    bf16x8 kr1 = *(const bf16x8*)&k[bh_qk + (size_t)(64 + sr0 + 32) * EE + se0];
    bf16x8 vr0 = *(const bf16x8*)&vt[bh_vt + 64 + (size_t)sr0 * SS + se0];
    bf16x8 vr1 = *(const bf16x8*)&vt[bh_vt + 64 + (size_t)(sr0 + 32) * SS + se0];

    f32x16 s[2];
#pragma unroll
    for (int kb = 0; kb < 2; ++kb) {
      f32x16 acc;
#pragma unroll
      for (int r = 0; r < 16; ++r) acc[r] = 0.f;
#pragma unroll
      for (int db = 0; db < 4; ++db) {
        bf16x8 ka = *(bf16x8*)&Ks[0][(kb * 32 + lq) * 72 + db * 16 + h2 * 8];
        acc = __builtin_amdgcn_mfma_f32_32x32x16_bf16(ka, aq[db], acc, 0, 0, 0);
      }
      s[kb] = acc;
    }
#pragma unroll
    for (int kb = 0; kb < 2; ++kb)
#pragma unroll
      for (int t16 = 0; t16 < 2; ++t16)
#pragma unroll
        for (int j2 = 0; j2 < 4; ++j2) {
          float pa = __builtin_amdgcn_exp2f(s[kb][t16 * 8 + j2 * 2]);
          float pb = __builtin_amdgcn_exp2f(s[kb][t16 * 8 + j2 * 2 + 1]);
          lacc[kb] += pa + pb;
          pwvP[kb][t16][j2] = cvt_pk(pa, pb);
        }
#pragma unroll
    for (int ct = 0; ct < 2; ++ct)
#pragma unroll
      for (int kb = 0; kb < 2; ++kb)
#pragma unroll
        for (int t16 = 0; t16 < 2; ++t16)
          vfP[ct][kb * 2 + t16] = *(bf16x8*)&Vts[0][(ct * 32 + lq) * 72 +
                                                    kb * 32 + t16 * 16 + h2 * 8];
    *(bf16x8*)&Ks[1][krow0 * 72 + se0] = kr0;
    *(bf16x8*)&Ks[1][(krow0 + 32) * 72 + se0] = kr1;
    *(bf16x8*)&Vts[1][sr0 * 72 + se0] = vr0;
    *(bf16x8*)&Vts[1][(sr0 + 32) * 72 + se0] = vr1;
    __syncthreads();
  }

  // ---- main loop: PV(t-1) FIRST (reg-only), then QK(t), exp(t) ----
  for (int t = 1; t < 32; ++t) {
    const int cur = t & 1;
    const int tn = (t + 1) & 31;  // wraps to 0 at t=31 (harmless extra stage)

    bf16x8 kr0, kr1, vr0, vr1;
    {
      const size_t kb2 = bh_qk + (size_t)(tn * 64) * EE;
      kr0 = *(const bf16x8*)&k[kb2 + (size_t)sr0 * EE + se0];
      kr1 = *(const bf16x8*)&k[kb2 + (size_t)(sr0 + 32) * EE + se0];
      const size_t vb2 = bh_vt + tn * 64;
      vr0 = *(const bf16x8*)&vt[vb2 + (size_t)sr0 * SS + se0];
      vr1 = *(const bf16x8*)&vt[vb2 + (size_t)(sr0 + 32) * SS + se0];
    }

    // PV(t-1): zero dependencies at barrier exit -> matrix pipe fills now
#pragma unroll
    for (int ct = 0; ct < 2; ++ct)
#pragma unroll
      for (int kb = 0; kb < 2; ++kb)
#pragma unroll
        for (int t16 = 0; t16 < 2; ++t16)
          accO[ct] = __builtin_amdgcn_mfma_f32_32x32x16_bf16(
              vfP[ct][kb * 2 + t16],
              __builtin_bit_cast(bf16x8, pwvP[kb][t16]), accO[ct], 0, 0, 0);

    // QK(t): K ds_read latency hid under PV above
    f32x16 s[2];
#pragma unroll
    for (int kb = 0; kb < 2; ++kb) {
      f32x16 acc;
#pragma unroll
      for (int r = 0; r < 16; ++r) acc[r] = 0.f;
#pragma unroll
      for (int db = 0; db < 4; ++db) {
        bf16x8 ka = *(bf16x8*)&Ks[cur][(kb * 32 + lq) * 72 + db * 16 + h2 * 8];
        acc = __builtin_amdgcn_mfma_f32_32x32x16_bf16(ka, aq[db], acc, 0, 0, 0);
      }
      s[kb] = acc;
    }

    // exp(t)
    u32x4 pwvC[2][2];
#pragma unroll
    for (int kb = 0; kb < 2; ++kb)
#pragma unroll
      for (int t16 = 0; t16 < 2; ++t16)
#pragma unroll
        for (int j2 = 0; j2 < 4; ++j2) {
          float pa = __builtin_amdgcn_exp2f(s[kb][t16 * 8 + j2 * 2]);
          float pb = __builtin_amdgcn_exp2f(s[kb][t16 * 8 + j2 * 2 + 1]);
          lacc[kb] += pa + pb;
          pwvC[kb][t16][j2] = cvt_pk(pa, pb);
        }

    // capture V(t) frags to regs (PV(t) runs next iter)
#pragma unroll
    for (int ct = 0; ct < 2; ++ct)
#pragma unroll
      for (int kb = 0; kb < 2; ++kb)
#pragma unroll
        for (int t16 = 0; t16 < 2; ++t16)
          vfP[ct][kb * 2 + t16] = *(bf16x8*)&Vts[cur][(ct * 32 + lq) * 72 +
                                                      kb * 32 + t16 * 16 + h2 * 8];

    // stage tile tn into the other buffer
    {
      const int nxt = cur ^ 1;
      *(bf16x8*)&Ks[nxt][krow0 * 72 + se0] = kr0;
      *(bf16x8*)&Ks[nxt][(krow0 + 32) * 72 + se0] = kr1;
      *(bf16x8*)&Vts[nxt][sr0 * 72 + se0] = vr0;
      *(bf16x8*)&Vts[nxt][(sr0 + 32) * 72 + se0] = vr1;
    }
    __syncthreads();

#pragma unroll
    for (int kb = 0; kb < 2; ++kb)
#pragma unroll
      for (int t16 = 0; t16 < 2; ++t16) pwvP[kb][t16] = pwvC[kb][t16];
  }

  // epilogue: PV(31)
#pragma unroll
  for (int ct = 0; ct < 2; ++ct)
#pragma unroll
    for (int kb = 0; kb < 2; ++kb)
#pragma unroll
      for (int t16 = 0; t16 < 2; ++t16)
        accO[ct] = __builtin_amdgcn_mfma_f32_32x32x16_bf16(
            vfP[ct][kb * 2 + t16],
            __builtin_bit_cast(bf16x8, pwvP[kb][t16]), accO[ct], 0, 0, 0);

  // normalize: wave halves hold complementary key sums for the same q
  {
    float tsum = lacc[0] + lacc[1];
    tsum += __shfl_xor(tsum, 32, 64);
    float inv = 1.f / tsum;
    size_t row = (size_t)b * SS + q0 + lq;
#pragma unroll
    for (int ct = 0; ct < 2; ++ct)
#pragma unroll
      for (int rq = 0; rq < 4; ++rq) {
        uint2 pk;
        pk.x = cvt_pk(accO[ct][rq * 4 + 0] * inv, accO[ct][rq * 4 + 1] * inv);
        pk.y = cvt_pk(accO[ct][rq * 4 + 2] * inv, accO[ct][rq * 4 + 3] * inv);
        *(uint2*)&o[row * EE + h * DD + ct * 32 + rq * 8 + h2 * 4] = pk;
      }
  }
}

// ---------------------------------------------------------------------------
// Kernel 5: output projection, bf16 MFMA GEMM, 128x64 tile, reg-staged
// double-buffer, 1 barrier per K-step.
// ---------------------------------------------------------------------------
__global__ __launch_bounds__(256) void out_proj_mfma(
    const ushort* __restrict__ a, const ushort* __restrict__ wo,
    const float* __restrict__ bias, float* __restrict__ y) {
  __shared__ __align__(16) ushort As[2][128 * 72];
  __shared__ __align__(16) ushort Ws[2][64 * 72];
  const int tid = threadIdx.x, w = tid >> 6, l = tid & 63;
  const int g = l >> 4, c = l & 15;
  const int m0 = blockIdx.x * 128, n0 = blockIdx.y * 64;
  const int sr = tid >> 3, se = (tid & 7) * 8;

  f32x4 acc[2][4];
#pragma unroll
  for (int mf = 0; mf < 2; ++mf)
#pragma unroll
    for (int ct = 0; ct < 4; ++ct) acc[mf][ct] = (f32x4){0.f, 0.f, 0.f, 0.f};

  {
#pragma unroll
    for (int j = 0; j < 4; ++j) {
      int r = sr + j * 32;
      *(bf16x8*)&As[0][r * 72 + se] = *(const bf16x8*)&a[(size_t)(m0 + r) * EE + se];
    }
#pragma unroll
    for (int j = 0; j < 2; ++j) {
      int r = sr + j * 32;
      *(bf16x8*)&Ws[0][r * 72 + se] = *(const bf16x8*)&wo[(size_t)(n0 + r) * EE + se];
    }
  }
  __syncthreads();

  for (int t = 0; t < 16; ++t) {
    const int cur = t & 1;
    bf16x8 Arg[4], Brg[2];
    if (t < 15) {
      const int k0 = (t + 1) * 64;
#pragma unroll
      for (int j = 0; j < 4; ++j) {
        int r = sr + j * 32;
        Arg[j] = *(const bf16x8*)&a[(size_t)(m0 + r) * EE + k0 + se];
      }
#pragma unroll
      for (int j = 0; j < 2; ++j) {
        int r = sr + j * 32;
        Brg[j] = *(const bf16x8*)&wo[(size_t)(n0 + r) * EE + k0 + se];
      }
    }

    bf16x8 af[2][2];
#pragma unroll
    for (int mf = 0; mf < 2; ++mf) {
      af[mf][0] = *(bf16x8*)&As[cur][(w * 32 + mf * 16 + c) * 72 + g * 8];
      af[mf][1] = *(bf16x8*)&As[cur][(w * 32 + mf * 16 + c) * 72 + 32 + g * 8];
    }
    __builtin_amdgcn_s_setprio(1);
#pragma unroll
    for (int ct = 0; ct < 4; ++ct) {
      bf16x8 b0 = *(bf16x8*)&Ws[cur][(ct * 16 + c) * 72 + g * 8];
      bf16x8 b1 = *(bf16x8*)&Ws[cur][(ct * 16 + c) * 72 + 32 + g * 8];
#pragma unroll
      for (int mf = 0; mf < 2; ++mf) {
        acc[mf][ct] = __builtin_amdgcn_mfma_f32_16x16x32_bf16(af[mf][0], b0, acc[mf][ct], 0, 0, 0);
        acc[mf][ct] = __builtin_amdgcn_mfma_f32_16x16x32_bf16(af[mf][1], b1, acc[mf][ct], 0, 0, 0);
      }
    }
    __builtin_amdgcn_s_setprio(0);

    if (t < 15) {
      const int nxt = cur ^ 1;
#pragma unroll
      for (int j = 0; j < 4; ++j) {
        int r = sr + j * 32;
        *(bf16x8*)&As[nxt][r * 72 + se] = Arg[j];
      }
#pragma unroll
      for (int j = 0; j < 2; ++j) {
        int r = sr + j * 32;
        *(bf16x8*)&Ws[nxt][r * 72 + se] = Brg[j];
      }
    }
    __syncthreads();
  }

#pragma unroll
  for (int ct = 0; ct < 4; ++ct) {
    float bv = bias[n0 + ct * 16 + c];
#pragma unroll
    for (int mf = 0; mf < 2; ++mf)
#pragma unroll
      for (int r = 0; r < 4; ++r)
        y[(size_t)(m0 + w * 32 + mf * 16 + g * 4 + r) * EE + n0 + ct * 16 + c] =
            acc[mf][ct][r] + bv;
  }
}

// ---------------------------------------------------------------------------
extern "C" void kernel_launch(void* const* d_in, const int* in_sizes, int n_in,
                              void* d_out, int out_size, void* d_ws,
                              size_t ws_size, hipStream_t stream) {
  const float* x = (const float*)d_in[0];
  const float* Wq = (const float*)d_in[1];
  const float* Wk = (const float*)d_in[2];
  const float* Wv = (const float*)d_in[3];
  const float* Wo = (const float*)d_in[4];
  const float* bo = (const float*)d_in[5];
  float* out = (float*)d_out;

  const size_t per = (size_t)NROWS * 64;  // 4,194,304 elems
  ushort* qb = (ushort*)d_ws;                       //  8 MB
  ushort* kb = qb + per;                            //  8 MB
  ushort* vtb = kb + per;                           //  8 MB
  ushort* aob = vtb + per;                          //  8 MB
  ushort* wob = aob + per;                          //  2 MB
  ushort* wqkvb = wob + 1024 * 1024;                // 24 KB

  wconv<<<518, 256, 0, stream>>>(Wq, Wk, Wv, Wo, wqkvb, wob);
  qkv_mfma<<<dim3(16, 16, 2), 256, 0, stream>>>(x, wqkvb, qb, kb, vtb);
  attn_mfma<<<512, 256, 0, stream>>>(qb, kb, vtb, aob);
  out_proj_mfma<<<dim3(32, 16), 256, 0, stream>>>(aob, wob, bo, out);
}

// Round 13
// 78.535 us; speedup vs baseline: 2.0406x; 1.0351x over previous
//
#include <hip/hip_runtime.h>
#include <math.h>

#define BB 2
#define SS 2048
#define EE 1024
#define HH 16
#define DD 64
constexpr int NROWS = BB * SS * HH;   // 65536 rows of D=64
// q pre-scale: (1/sqrt(E)) * log2(e) so attention can use exp2 directly
constexpr float SCALE_Q = 1.4426950408889634f / 32.0f;

typedef __attribute__((ext_vector_type(8))) short bf16x8;
typedef __attribute__((ext_vector_type(4))) float f32x4;
typedef __attribute__((ext_vector_type(16))) float f32x16;
typedef __attribute__((ext_vector_type(4))) unsigned u32x4;

// packed f32x2 -> bf16x2 (RNE), one VALU inst
__device__ inline unsigned cvt_pk(float lo, float hi) {
  unsigned r;
  asm("v_cvt_pk_bf16_f32 %0, %1, %2" : "=v"(r) : "v"(lo), "v"(hi));
  return r;
}

// ---------------------------------------------------------------------------
// Kernel 1: QKV projection, h-major blocks (fixed b,h; 128 s-rows).
// Weights converted fp32->bf16 INLINE during LDS staging (wconv deleted).
// Each block also converts 2048 elems of W_out (hides in memory-bound phase).
// q,k via swapped operands -> packed uint2 stores; V written TRANSPOSED
// [B,H,D,S] via the unswapped form.
// ---------------------------------------------------------------------------
__global__ __launch_bounds__(256) void qkv_mfma(
    const float* __restrict__ x,
    const float* __restrict__ Wq, const float* __restrict__ Wk,
    const float* __restrict__ Wv, const float* __restrict__ Wo,
    ushort* __restrict__ qo, ushort* __restrict__ ko, ushort* __restrict__ vto,
    ushort* __restrict__ wob) {
  __shared__ __align__(16) ushort Xs[128 * 72];
  __shared__ __align__(16) ushort Ws[3][64 * 72];
  const int tid = threadIdx.x, w = tid >> 6, l = tid & 63;
  const int g = l >> 4, c = l & 15;
  const int s0 = blockIdx.x * 128, h = blockIdx.y, b = blockIdx.z;

  // W_out conversion slice: 512 blocks x 2048 elems = 1M
  {
    const int lin = blockIdx.x + (blockIdx.y << 4) + (blockIdx.z << 8);
    const size_t base = (size_t)lin * 2048 + tid * 8;
    float4 a = *(const float4*)&Wo[base];
    float4 cc = *(const float4*)&Wo[base + 4];
    u32x4 r;
    r[0] = cvt_pk(a.x, a.y);
    r[1] = cvt_pk(a.z, a.w);
    r[2] = cvt_pk(cc.x, cc.y);
    r[3] = cvt_pk(cc.z, cc.w);
    *(u32x4*)&wob[base] = r;
  }

  // stage Wq/Wk/Wv fp32 -> bf16 LDS
  for (int i = tid; i < 1536; i += 256) {
    int t = i >> 9, j = i & 511;
    int r = j >> 3, e0 = (j & 7) * 8;
    const float* W = (t == 0) ? Wq : ((t == 1) ? Wk : Wv);
    float4 va = *(const float4*)&W[r * 64 + e0];
    float4 vb = *(const float4*)&W[r * 64 + e0 + 4];
    u32x4 pk;
    pk[0] = cvt_pk(va.x, va.y);
    pk[1] = cvt_pk(va.z, va.w);
    pk[2] = cvt_pk(vb.x, vb.y);
    pk[3] = cvt_pk(vb.z, vb.w);
    *(u32x4*)&Ws[t][r * 72 + e0] = pk;
  }
  for (int i = tid; i < 2048; i += 256) {
    int r = i >> 4, c4 = (i & 15) * 4;
    float4 xv = *(const float4*)&x[(((size_t)b * SS + s0 + r) * HH + h) * DD + c4];
    uint2 pk;
    pk.x = cvt_pk(xv.x, xv.y);
    pk.y = cvt_pk(xv.z, xv.w);
    *(uint2*)&Xs[r * 72 + c4] = pk;
  }
  __syncthreads();

  bf16x8 a_[2][2];
#pragma unroll
  for (int rf = 0; rf < 2; ++rf) {
    a_[rf][0] = *(bf16x8*)&Xs[(w * 32 + rf * 16 + c) * 72 + g * 8];
    a_[rf][1] = *(bf16x8*)&Xs[(w * 32 + rf * 16 + c) * 72 + 32 + g * 8];
  }

  // q and k: swapped operands -> lane holds s-row c, 4 consecutive e
#pragma unroll
  for (int t = 0; t < 2; ++t) {
    ushort* out = (t == 0) ? qo : ko;
    const float sc = (t == 0) ? SCALE_Q : 1.0f;
#pragma unroll
    for (int ct = 0; ct < 4; ++ct) {
      bf16x8 b0 = *(bf16x8*)&Ws[t][(ct * 16 + c) * 72 + g * 8];
      bf16x8 b1 = *(bf16x8*)&Ws[t][(ct * 16 + c) * 72 + 32 + g * 8];
#pragma unroll
      for (int rf = 0; rf < 2; ++rf) {
        f32x4 acc = (f32x4){0.f, 0.f, 0.f, 0.f};
        acc = __builtin_amdgcn_mfma_f32_16x16x32_bf16(b0, a_[rf][0], acc, 0, 0, 0);
        acc = __builtin_amdgcn_mfma_f32_16x16x32_bf16(b1, a_[rf][1], acc, 0, 0, 0);
        uint2 pk;
        pk.x = cvt_pk(acc[0] * sc, acc[1] * sc);
        pk.y = cvt_pk(acc[2] * sc, acc[3] * sc);
        int srow = s0 + w * 32 + rf * 16 + c;
        *(uint2*)&out[((size_t)b * SS + srow) * EE + h * DD + ct * 16 + g * 4] = pk;
      }
    }
  }
  // v: transposed [B,H,D,S], packed 8B stores (unswapped form)
#pragma unroll
  for (int ct = 0; ct < 4; ++ct) {
    bf16x8 b0 = *(bf16x8*)&Ws[2][(ct * 16 + c) * 72 + g * 8];
    bf16x8 b1 = *(bf16x8*)&Ws[2][(ct * 16 + c) * 72 + 32 + g * 8];
#pragma unroll
    for (int rf = 0; rf < 2; ++rf) {
      f32x4 acc = (f32x4){0.f, 0.f, 0.f, 0.f};
      acc = __builtin_amdgcn_mfma_f32_16x16x32_bf16(a_[rf][0], b0, acc, 0, 0, 0);
      acc = __builtin_amdgcn_mfma_f32_16x16x32_bf16(a_[rf][1], b1, acc, 0, 0, 0);
      uint2 pk;
      pk.x = cvt_pk(acc[0], acc[1]);
      pk.y = cvt_pk(acc[2], acc[3]);
      int d = ct * 16 + c;
      int srow = w * 32 + rf * 16 + g * 4;
      *(uint2*)&vto[(((size_t)b * HH + h) * DD + d) * SS + s0 + srow] = pk;
    }
  }
}

// ---------------------------------------------------------------------------
// Kernel 4: MFMA flash attention (unchanged from r12: 32x32x16, swapped
// S^T = K·Q^T, software-pipelined softmax, PV-first, 1 barrier/iter).
// ---------------------------------------------------------------------------
__global__ __launch_bounds__(256) void attn_mfma(
    const ushort* __restrict__ q, const ushort* __restrict__ k,
    const ushort* __restrict__ vt, ushort* __restrict__ o) {
  __shared__ __align__(16) ushort Ks[2][64 * 72];
  __shared__ __align__(16) ushort Vts[2][64 * 72];
  const int tid = threadIdx.x, w = tid >> 6, l = tid & 63;
  const int lq = l & 31, h2 = l >> 5;  // q-col / key-row-half
  // XCD swizzle: blockIdx%8 = XCD -> contiguous chunk of 64 works
  const int work = ((blockIdx.x & 7) << 6) | (blockIdx.x >> 3);
  const int qt = work & 15, hb = work >> 4;
  const int h = hb & 15, b = hb >> 4;
  const int q0 = qt * 128 + w * 32;

  const size_t bh_qk = (size_t)b * SS * EE + h * DD;        // + s*EE + d
  const size_t bh_vt = (size_t)b * SS * EE + h * (DD * SS); // + d*SS + s

  const int sr0 = tid >> 3;            // 0..31
  const int se0 = (tid & 7) * 8;
  // sigma: swap bits 2 and 3 of the key index (bits 0,1,4 kept)
  const int krow0 = (sr0 & 19) | ((sr0 & 4) << 1) | ((sr0 & 8) >> 1);

  // prologue: stage tile 0
  {
    bf16x8 kr0 = *(const bf16x8*)&k[bh_qk + (size_t)sr0 * EE + se0];
    bf16x8 kr1 = *(const bf16x8*)&k[bh_qk + (size_t)(sr0 + 32) * EE + se0];
    bf16x8 vr0 = *(const bf16x8*)&vt[bh_vt + (size_t)sr0 * SS + se0];
    bf16x8 vr1 = *(const bf16x8*)&vt[bh_vt + (size_t)(sr0 + 32) * SS + se0];
    *(bf16x8*)&Ks[0][krow0 * 72 + se0] = kr0;
    *(bf16x8*)&Ks[0][(krow0 + 32) * 72 + se0] = kr1;
    *(bf16x8*)&Vts[0][sr0 * 72 + se0] = vr0;
    *(bf16x8*)&Vts[0][(sr0 + 32) * 72 + se0] = vr1;
  }

  // Q B-frags: lane's q-row = q0 + lq
  bf16x8 aq[4];
#pragma unroll
  for (int db = 0; db < 4; ++db)
    aq[db] = *(const bf16x8*)&q[bh_qk + (size_t)(q0 + lq) * EE + db * 16 + h2 * 8];

  f32x16 accO[2];
  float lacc[2] = {0.f, 0.f};
#pragma unroll
  for (int ct = 0; ct < 2; ++ct)
#pragma unroll
    for (int r = 0; r < 16; ++r) accO[ct][r] = 0.f;

  u32x4 pwvP[2][2];   // previous tile's P (PV operands)
  bf16x8 vfP[2][4];   // previous tile's V frags [ct][kb*2+t16]

  __syncthreads();

  // ---- iter 0 (peeled: QK+exp only, capture V frags; no PV) ----
  {
    bf16x8 kr0 = *(const bf16x8*)&k[bh_qk + (size_t)(64 + sr0) * EE + se0];
    bf16x8 kr1 = *(const bf16x8*)&k[bh_qk + (size_t)(64 + sr0 + 32) * EE + se0];
    bf16x8 vr0 = *(const bf16x8*)&vt[bh_vt + 64 + (size_t)sr0 * SS + se0];
    bf16x8 vr1 = *(const bf16x8*)&vt[bh_vt + 64 + (size_t)(sr0 + 32) * SS + se0];

    f32x16 s[2];
#pragma unroll
    for (int kb = 0; kb < 2; ++kb) {
      f32x16 acc;
#pragma unroll
      for (int r = 0; r < 16; ++r) acc[r] = 0.f;
#pragma unroll
      for (int db = 0; db < 4; ++db) {
        bf16x8 ka = *(bf16x8*)&Ks[0][(kb * 32 + lq) * 72 + db * 16 + h2 * 8];
        acc = __builtin_amdgcn_mfma_f32_32x32x16_bf16(ka, aq[db], acc, 0, 0, 0);
      }
      s[kb] = acc;
    }
#pragma unroll
    for (int kb = 0; kb < 2; ++kb)
#pragma unroll
      for (int t16 = 0; t16 < 2; ++t16)
#pragma unroll
        for (int j2 = 0; j2 < 4; ++j2) {
          float pa = __builtin_amdgcn_exp2f(s[kb][t16 * 8 + j2 * 2]);
          float pb = __builtin_amdgcn_exp2f(s[kb][t16 * 8 + j2 * 2 + 1]);
          lacc[kb] += pa + pb;
          pwvP[kb][t16][j2] = cvt_pk(pa, pb);
        }
#pragma unroll
    for (int ct = 0; ct < 2; ++ct)
#pragma unroll
      for (int kb = 0; kb < 2; ++kb)
#pragma unroll
        for (int t16 = 0; t16 < 2; ++t16)
          vfP[ct][kb * 2 + t16] = *(bf16x8*)&Vts[0][(ct * 32 + lq) * 72 +
                                                    kb * 32 + t16 * 16 + h2 * 8];
    *(bf16x8*)&Ks[1][krow0 * 72 + se0] = kr0;
    *(bf16x8*)&Ks[1][(krow0 + 32) * 72 + se0] = kr1;
    *(bf16x8*)&Vts[1][sr0 * 72 + se0] = vr0;
    *(bf16x8*)&Vts[1][(sr0 + 32) * 72 + se0] = vr1;
    __syncthreads();
  }

  // ---- main loop: PV(t-1) FIRST (reg-only), then QK(t), exp(t) ----
  for (int t = 1; t < 32; ++t) {
    const int cur = t & 1;
    const int tn = (t + 1) & 31;  // wraps to 0 at t=31 (harmless extra stage)

    bf16x8 kr0, kr1, vr0, vr1;
    {
      const size_t kb2 = bh_qk + (size_t)(tn * 64) * EE;
      kr0 = *(const bf16x8*)&k[kb2 + (size_t)sr0 * EE + se0];
      kr1 = *(const bf16x8*)&k[kb2 + (size_t)(sr0 + 32) * EE + se0];
      const size_t vb2 = bh_vt + tn * 64;
      vr0 = *(const bf16x8*)&vt[vb2 + (size_t)sr0 * SS + se0];
      vr1 = *(const bf16x8*)&vt[vb2 + (size_t)(sr0 + 32) * SS + se0];
    }

    // PV(t-1): zero dependencies at barrier exit -> matrix pipe fills now
#pragma unroll
    for (int ct = 0; ct < 2; ++ct)
#pragma unroll
      for (int kb = 0; kb < 2; ++kb)
#pragma unroll
        for (int t16 = 0; t16 < 2; ++t16)
          accO[ct] = __builtin_amdgcn_mfma_f32_32x32x16_bf16(
              vfP[ct][kb * 2 + t16],
              __builtin_bit_cast(bf16x8, pwvP[kb][t16]), accO[ct], 0, 0, 0);

    // QK(t)
    f32x16 s[2];
#pragma unroll
    for (int kb = 0; kb < 2; ++kb) {
      f32x16 acc;
#pragma unroll
      for (int r = 0; r < 16; ++r) acc[r] = 0.f;
#pragma unroll
      for (int db = 0; db < 4; ++db) {
        bf16x8 ka = *(bf16x8*)&Ks[cur][(kb * 32 + lq) * 72 + db * 16 + h2 * 8];
        acc = __builtin_amdgcn_mfma_f32_32x32x16_bf16(ka, aq[db], acc, 0, 0, 0);
      }
      s[kb] = acc;
    }

    // exp(t)
    u32x4 pwvC[2][2];
#pragma unroll
    for (int kb = 0; kb < 2; ++kb)
#pragma unroll
      for (int t16 = 0; t16 < 2; ++t16)
#pragma unroll
        for (int j2 = 0; j2 < 4; ++j2) {
          float pa = __builtin_amdgcn_exp2f(s[kb][t16 * 8 + j2 * 2]);
          float pb = __builtin_amdgcn_exp2f(s[kb][t16 * 8 + j2 * 2 + 1]);
          lacc[kb] += pa + pb;
          pwvC[kb][t16][j2] = cvt_pk(pa, pb);
        }

    // capture V(t) frags to regs (PV(t) runs next iter)
#pragma unroll
    for (int ct = 0; ct < 2; ++ct)
#pragma unroll
      for (int kb = 0; kb < 2; ++kb)
#pragma unroll
        for (int t16 = 0; t16 < 2; ++t16)
          vfP[ct][kb * 2 + t16] = *(bf16x8*)&Vts[cur][(ct * 32 + lq) * 72 +
                                                      kb * 32 + t16 * 16 + h2 * 8];

    // stage tile tn into the other buffer
    {
      const int nxt = cur ^ 1;
      *(bf16x8*)&Ks[nxt][krow0 * 72 + se0] = kr0;
      *(bf16x8*)&Ks[nxt][(krow0 + 32) * 72 + se0] = kr1;
      *(bf16x8*)&Vts[nxt][sr0 * 72 + se0] = vr0;
      *(bf16x8*)&Vts[nxt][(sr0 + 32) * 72 + se0] = vr1;
    }
    __syncthreads();

#pragma unroll
    for (int kb = 0; kb < 2; ++kb)
#pragma unroll
      for (int t16 = 0; t16 < 2; ++t16) pwvP[kb][t16] = pwvC[kb][t16];
  }

  // epilogue: PV(31)
#pragma unroll
  for (int ct = 0; ct < 2; ++ct)
#pragma unroll
    for (int kb = 0; kb < 2; ++kb)
#pragma unroll
      for (int t16 = 0; t16 < 2; ++t16)
        accO[ct] = __builtin_amdgcn_mfma_f32_32x32x16_bf16(
            vfP[ct][kb * 2 + t16],
            __builtin_bit_cast(bf16x8, pwvP[kb][t16]), accO[ct], 0, 0, 0);

  // normalize: wave halves hold complementary key sums for the same q
  {
    float tsum = lacc[0] + lacc[1];
    tsum += __shfl_xor(tsum, 32, 64);
    float inv = 1.f / tsum;
    size_t row = (size_t)b * SS + q0 + lq;
#pragma unroll
    for (int ct = 0; ct < 2; ++ct)
#pragma unroll
      for (int rq = 0; rq < 4; ++rq) {
        uint2 pk;
        pk.x = cvt_pk(accO[ct][rq * 4 + 0] * inv, accO[ct][rq * 4 + 1] * inv);
        pk.y = cvt_pk(accO[ct][rq * 4 + 2] * inv, accO[ct][rq * 4 + 3] * inv);
        *(uint2*)&o[row * EE + h * DD + ct * 32 + rq * 8 + h2 * 4] = pk;
      }
  }
}

// ---------------------------------------------------------------------------
// Kernel 5: output projection, 32x32x16 MFMA with swapped operands + sigma
// W staging (attn's proven pattern): lane holds one m-row, 8 consecutive n
// per (kb,t16) -> float4 stores. 128x64 tile, reg-staged dbuf, 1 barrier/step.
// ---------------------------------------------------------------------------
__global__ __launch_bounds__(256) void out_proj_mfma(
    const ushort* __restrict__ a, const ushort* __restrict__ wo,
    const float* __restrict__ bias, float* __restrict__ y) {
  __shared__ __align__(16) ushort As[2][128 * 72];
  __shared__ __align__(16) ushort Ws[2][64 * 72];
  const int tid = threadIdx.x, w = tid >> 6, l = tid & 63;
  const int lq = l & 31, h2 = l >> 5;
  const int m0 = blockIdx.x * 128, n0 = blockIdx.y * 64;
  const int sr = tid >> 3, se = (tid & 7) * 8;
  // sigma: swap bits 2,3 of the W-row (n) index within its 32-block
  const int krow = (sr & 19) | ((sr & 4) << 1) | ((sr & 8) >> 1);

  f32x16 acc[2];
#pragma unroll
  for (int kb = 0; kb < 2; ++kb)
#pragma unroll
    for (int r = 0; r < 16; ++r) acc[kb][r] = 0.f;

  // prologue: stage k0=0 into buf 0
  {
#pragma unroll
    for (int j = 0; j < 4; ++j) {
      int r = sr + j * 32;
      *(bf16x8*)&As[0][r * 72 + se] = *(const bf16x8*)&a[(size_t)(m0 + r) * EE + se];
    }
    *(bf16x8*)&Ws[0][krow * 72 + se] = *(const bf16x8*)&wo[(size_t)(n0 + sr) * EE + se];
    *(bf16x8*)&Ws[0][(krow + 32) * 72 + se] =
        *(const bf16x8*)&wo[(size_t)(n0 + sr + 32) * EE + se];
  }
  __syncthreads();

  for (int t = 0; t < 16; ++t) {
    const int cur = t & 1;
    bf16x8 Arg[4], Brg[2];
    if (t < 15) {
      const int k0 = (t + 1) * 64;
#pragma unroll
      for (int j = 0; j < 4; ++j) {
        int r = sr + j * 32;
        Arg[j] = *(const bf16x8*)&a[(size_t)(m0 + r) * EE + k0 + se];
      }
      Brg[0] = *(const bf16x8*)&wo[(size_t)(n0 + sr) * EE + k0 + se];
      Brg[1] = *(const bf16x8*)&wo[(size_t)(n0 + sr + 32) * EE + k0 + se];
    }

    // frags: W as A-operand (rows=n, sigma'd), A as B-operand (cols=m)
    bf16x8 af[4];
#pragma unroll
    for (int db = 0; db < 4; ++db)
      af[db] = *(bf16x8*)&As[cur][(w * 32 + lq) * 72 + db * 16 + h2 * 8];
#pragma unroll
    for (int kb = 0; kb < 2; ++kb)
#pragma unroll
      for (int db = 0; db < 4; ++db) {
        bf16x8 wf = *(bf16x8*)&Ws[cur][(kb * 32 + lq) * 72 + db * 16 + h2 * 8];
        acc[kb] = __builtin_amdgcn_mfma_f32_32x32x16_bf16(wf, af[db], acc[kb], 0, 0, 0);
      }

    if (t < 15) {
      const int nxt = cur ^ 1;
#pragma unroll
      for (int j = 0; j < 4; ++j) {
        int r = sr + j * 32;
        *(bf16x8*)&As[nxt][r * 72 + se] = Arg[j];
      }
      *(bf16x8*)&Ws[nxt][krow * 72 + se] = Brg[0];
      *(bf16x8*)&Ws[nxt][(krow + 32) * 72 + se] = Brg[1];
    }
    __syncthreads();
  }

  // epilogue: lane owns m-row m0+w*32+lq; regs t16*8+j -> n = kb*32+t16*16+h2*8+j
  const size_t row = (size_t)(m0 + w * 32 + lq) * EE;
#pragma unroll
  for (int kb = 0; kb < 2; ++kb)
#pragma unroll
    for (int t16 = 0; t16 < 2; ++t16) {
      const int nb = n0 + kb * 32 + t16 * 16 + h2 * 8;
      float4 bv0 = *(const float4*)&bias[nb];
      float4 bv1 = *(const float4*)&bias[nb + 4];
      float4 o0 = {acc[kb][t16 * 8 + 0] + bv0.x, acc[kb][t16 * 8 + 1] + bv0.y,
                   acc[kb][t16 * 8 + 2] + bv0.z, acc[kb][t16 * 8 + 3] + bv0.w};
      float4 o1 = {acc[kb][t16 * 8 + 4] + bv1.x, acc[kb][t16 * 8 + 5] + bv1.y,
                   acc[kb][t16 * 8 + 6] + bv1.z, acc[kb][t16 * 8 + 7] + bv1.w};
      *(float4*)&y[row + nb] = o0;
      *(float4*)&y[row + nb + 4] = o1;
    }
}

// ---------------------------------------------------------------------------
extern "C" void kernel_launch(void* const* d_in, const int* in_sizes, int n_in,
                              void* d_out, int out_size, void* d_ws,
                              size_t ws_size, hipStream_t stream) {
  const float* x = (const float*)d_in[0];
  const float* Wq = (const float*)d_in[1];
  const float* Wk = (const float*)d_in[2];
  const float* Wv = (const float*)d_in[3];
  const float* Wo = (const float*)d_in[4];
  const float* bo = (const float*)d_in[5];
  float* out = (float*)d_out;

  const size_t per = (size_t)NROWS * 64;  // 4,194,304 elems
  ushort* qb = (ushort*)d_ws;                       //  8 MB
  ushort* kb = qb + per;                            //  8 MB
  ushort* vtb = kb + per;                           //  8 MB
  ushort* aob = vtb + per;                          //  8 MB
  ushort* wob = aob + per;                          //  2 MB

  qkv_mfma<<<dim3(16, 16, 2), 256, 0, stream>>>(x, Wq, Wk, Wv, Wo,
                                                qb, kb, vtb, wob);
  attn_mfma<<<512, 256, 0, stream>>>(qb, kb, vtb, aob);
  out_proj_mfma<<<dim3(32, 16), 256, 0, stream>>>(aob, wob, bo, out);
}